// Round 8
// baseline (2341.094 us; speedup 1.0000x reference)
//
#include <hip/hip_runtime.h>

#define N_VEC 131072   // B*H*W
#define DIM   64
#define KCODE 1024
#define HW    4096
#define DHW   262144
#define EPS   0.125f   // near-tie margin (validated r4-r8)
#define WLCAP 32768
#define BLK_ROWS 128   // rows per block; 4 waves x 32 rows
#define PITCH 72       // shorts per LDS row (144 B)
#define BCHUNK 64      // main: codes per LDS-staged codebook chunk
#define NBCHUNK 16

typedef short short8 __attribute__((ext_vector_type(8)));
typedef float f32x4  __attribute__((ext_vector_type(4)));

// ws layout (bytes) -- NEVER exceeds the proven 401408 footprint:
//   0      : double loss accumulator
//   8      : int flagged counter
//   12     : int done-ticket counter
//   64     : norms f32[1024]
//   8192   : eh  bf16-bits short[65536]   } after vq_main completes, this
//   139264 : el  bf16-bits short[65536]   } 256KB region is DEAD and is
//                                          reused as cbT f32[64][1024]
//   270336 : worklist int[WLCAP=32768]    (ends 401408)

__device__ __forceinline__ unsigned short f32_to_bf16_rne(float x) {
    unsigned u = __float_as_uint(x);
    u += 0x7FFFu + ((u >> 16) & 1u);
    return (unsigned short)(u >> 16);
}
__device__ __forceinline__ float bf16_to_f32(unsigned short h) {
    return __uint_as_float((unsigned)h << 16);
}

__global__ __launch_bounds__(256) void vq_prep(
    const float* __restrict__ cb, float* __restrict__ norms,
    short* __restrict__ ehg, short* __restrict__ elg,
    double* __restrict__ loss_acc, int* __restrict__ counter,
    int* __restrict__ done)
{
    const int t = threadIdx.x;
    if (blockIdx.x == 0 && t == 0) { *loss_acc = 0.0; *counter = 0; *done = 0; }

    const int k    = blockIdx.x * 16 + (t >> 4);
    const int part = t & 15;
    const float4 v = *(const float4*)(cb + k * DIM + part * 4);

    float s = 0.f;
    s = fmaf(v.x, v.x, s); s = fmaf(v.y, v.y, s);
    s = fmaf(v.z, v.z, s); s = fmaf(v.w, v.w, s);
    #pragma unroll
    for (int m = 1; m <= 8; m <<= 1) s += __shfl_xor(s, m, 64);
    if (part == 0) norms[k] = s;

    short h[4], l[4];
    const float vv[4] = { v.x, v.y, v.z, v.w };
    #pragma unroll
    for (int j = 0; j < 4; ++j) {
        unsigned short hh = f32_to_bf16_rne(vv[j]);
        unsigned short ll = f32_to_bf16_rne(vv[j] - bf16_to_f32(hh));
        h[j] = (short)hh; l[j] = (short)ll;
    }
    *(short4*)(ehg + k * DIM + part * 4) = make_short4(h[0], h[1], h[2], h[3]);
    *(short4*)(elg + k * DIM + part * 4) = make_short4(l[0], l[1], l[2], l[3]);
}

// Main v6 (unchanged from R5/R6): LDS-staged B double-buffered, per-block LDS
// aggregation of worklist slots -> ONE global atomicAdd per block.
__global__ __launch_bounds__(256, 2) void vq_main(
    const float* __restrict__ z, const float* __restrict__ cb,
    const float* __restrict__ norms, const short* __restrict__ ehg,
    const short* __restrict__ elg, float* __restrict__ out,
    double* __restrict__ loss_acc, int* __restrict__ counter,
    int* __restrict__ worklist, int cap)
{
    __shared__ short  zh[BLK_ROWS * PITCH];   // hi(-2z) bf16 bits, [row=hw][d]
    __shared__ short  zl[BLK_ROWS * PITCH];
    __shared__ short  ebh0[BCHUNK * PITCH];   // codebook chunk hi, double-buffered
    __shared__ short  ebh1[BCHUNK * PITCH];
    __shared__ short  ebl0[BCHUNK * PITCH];
    __shared__ short  ebl1[BCHUNK * PITCH];
    __shared__ float  nsh[KCODE];             // norms, block-resident
    __shared__ int    kidx[BLK_ROWS];
    __shared__ float  wsum[4];
    __shared__ int    blkrows[BLK_ROWS];      // flagged row-local ids
    __shared__ int    blkcnt;
    __shared__ int    blkbase;

    const int t   = threadIdx.x;              // 0..255
    const int n0  = blockIdx.x * BLK_ROWS;
    const int b   = n0 >> 12;
    const int hw0 = n0 & 4095;

    const int lane = t & 63;
    const int wave = t >> 6;                  // 0..3
    const int l15  = lane & 15;
    const int quad = lane >> 4;
    const int rowbase = wave * 32;            // 2 row-tiles per wave

    if (t == 0) blkcnt = 0;

    // ---- stage z -> LDS (8 float4/thread, register transpose, b128 writes) ----
    {
        const int hwl   = (t & 31) * 4;       // 4 consecutive rows
        const int dbase = (t >> 5) * 8;       // 8 consecutive d
        float4 v[8];
        #pragma unroll
        for (int p = 0; p < 8; ++p)
            v[p] = *(const float4*)(z + (size_t)b * DHW + (size_t)(dbase + p) * HW + hw0 + hwl);
        #pragma unroll
        for (int c = 0; c < 4; ++c) {
            short8 hi, lo;
            #pragma unroll
            for (int p = 0; p < 8; ++p) {
                const float* vp = (const float*)&v[p];
                float f = -2.0f * vp[c];
                unsigned short hh = f32_to_bf16_rne(f);
                unsigned short ll = f32_to_bf16_rne(f - bf16_to_f32(hh));
                hi[p] = (short)hh; lo[p] = (short)ll;
            }
            *(short8*)&zh[(hwl + c) * PITCH + dbase] = hi;
            *(short8*)&zl[(hwl + c) * PITCH + dbase] = lo;
        }
    }

    // ---- stage norms -> LDS ----
    #pragma unroll
    for (int j = 0; j < 4; ++j) nsh[t + j * 256] = norms[t + j * 256];

    // ---- B-staging prologue: thread owns 32 B hi + 32 B lo per chunk ----
    const int cc = t >> 2;                    // code within chunk (0..63)
    const int pp = (t & 3) * 16;              // short offset within code row
    short8 pf0[4], pf1[4];                    // [0..1]=hi, [2..3]=lo
    #pragma unroll
    for (int j = 0; j < 2; ++j) {
        pf0[j]     = *(const short8*)(ehg + (size_t)cc * DIM + pp + j * 8);
        pf0[2 + j] = *(const short8*)(elg + (size_t)cc * DIM + pp + j * 8);
        pf1[j]     = *(const short8*)(ehg + (size_t)(BCHUNK + cc) * DIM + pp + j * 8);
        pf1[2 + j] = *(const short8*)(elg + (size_t)(BCHUNK + cc) * DIM + pp + j * 8);
    }
    __syncthreads();                          // z + norms ready (prologue loads drain once)

    // ---- A-fragments (32 VGPRs, resident) ----
    short8 a_h[2][2], a_l[2][2];
    #pragma unroll
    for (int rt = 0; rt < 2; ++rt)
        #pragma unroll
        for (int kt = 0; kt < 2; ++kt) {
            const int idx = (rowbase + rt * 16 + l15) * PITCH + kt * 32 + quad * 8;
            a_h[rt][kt] = *(const short8*)&zh[idx];
            a_l[rt][kt] = *(const short8*)&zl[idx];
        }

    // ---- write chunk 0 into buf0 ----
    #pragma unroll
    for (int j = 0; j < 2; ++j) {
        *(short8*)&ebh0[cc * PITCH + pp + j * 8] = pf0[j];
        *(short8*)&ebl0[cc * PITCH + pp + j * 8] = pf0[2 + j];
    }
    __syncthreads();                          // buf0 ready

    float best[2][4], best2[2][4];
    #pragma unroll
    for (int rt = 0; rt < 2; ++rt)
        #pragma unroll
        for (int r = 0; r < 4; ++r) { best[rt][r] = 3.0e38f; best2[rt][r] = 3.0e38f; }

    // chunk body: issue ch+2 loads -> pfL; compute chunk ch from (bhR,blR);
    // write pfW (chunk ch+1) -> (bhW,blW); barrier.
    auto body = [&](int ch, const short* bhR, const short* blR,
                    short* bhW, short* blW, short8 (&pfL)[4], short8 (&pfW)[4]) {
        if (ch + 2 < NBCHUNK) {
            const size_t gb = (size_t)((ch + 2) * BCHUNK + cc) * DIM + pp;
            #pragma unroll
            for (int j = 0; j < 2; ++j) {
                pfL[j]     = *(const short8*)(ehg + gb + j * 8);
                pfL[2 + j] = *(const short8*)(elg + gb + j * 8);
            }
        }
        // hoist the 4 norm reads (they gate each MFMA chain's acc init)
        float nrm4[4];
        #pragma unroll
        for (int ct = 0; ct < 4; ++ct) nrm4[ct] = nsh[ch * BCHUNK + ct * 16 + l15];

        #pragma unroll
        for (int ct = 0; ct < 4; ++ct) {
            const int crow = ct * 16 + l15;
            short8 Bh0 = *(const short8*)&bhR[crow * PITCH + quad * 8];
            short8 Bh1 = *(const short8*)&bhR[crow * PITCH + 32 + quad * 8];
            short8 Bl0 = *(const short8*)&blR[crow * PITCH + quad * 8];
            short8 Bl1 = *(const short8*)&blR[crow * PITCH + 32 + quad * 8];
            const unsigned colbits = (unsigned)(ch * BCHUNK + crow);
            const float nrm = nrm4[ct];
            #pragma unroll
            for (int rt = 0; rt < 2; ++rt) {
                f32x4 acc = { nrm, nrm, nrm, nrm };
                acc = __builtin_amdgcn_mfma_f32_16x16x32_bf16(a_h[rt][0], Bh0, acc, 0, 0, 0);
                acc = __builtin_amdgcn_mfma_f32_16x16x32_bf16(a_h[rt][1], Bh1, acc, 0, 0, 0);
                acc = __builtin_amdgcn_mfma_f32_16x16x32_bf16(a_h[rt][0], Bl0, acc, 0, 0, 0);
                acc = __builtin_amdgcn_mfma_f32_16x16x32_bf16(a_h[rt][1], Bl1, acc, 0, 0, 0);
                acc = __builtin_amdgcn_mfma_f32_16x16x32_bf16(a_l[rt][0], Bh0, acc, 0, 0, 0);
                acc = __builtin_amdgcn_mfma_f32_16x16x32_bf16(a_l[rt][1], Bh1, acc, 0, 0, 0);
                #pragma unroll
                for (int r = 0; r < 4; ++r) {
                    float p = __uint_as_float((__float_as_uint(acc[r]) & 0xFFFFFC00u) | colbits);
                    best2[rt][r] = fminf(best2[rt][r], fmaxf(best[rt][r], p));
                    best[rt][r]  = fminf(best[rt][r], p);
                }
            }
        }
        if (ch + 1 < NBCHUNK) {
            #pragma unroll
            for (int j = 0; j < 2; ++j) {
                *(short8*)&bhW[cc * PITCH + pp + j * 8] = pfW[j];
                *(short8*)&blW[cc * PITCH + pp + j * 8] = pfW[2 + j];
            }
        }
        __syncthreads();
    };

    for (int chp = 0; chp < 8; ++chp) {
        body(2 * chp,     ebh0, ebl0, ebh1, ebl1, pf0, pf1);
        body(2 * chp + 1, ebh1, ebl1, ebh0, ebl0, pf1, pf0);
    }

    // ---- merge across 16 code-lanes; each wave has complete top-2 for its rows ----
    #pragma unroll
    for (int rt = 0; rt < 2; ++rt)
        #pragma unroll
        for (int r = 0; r < 4; ++r) {
            float bb = best[rt][r], b2 = best2[rt][r];
            #pragma unroll
            for (int m = 1; m <= 8; m <<= 1) {
                float ob  = __shfl_xor(bb, m, 64);
                float ob2 = __shfl_xor(b2, m, 64);
                b2 = fminf(fminf(b2, ob2), fmaxf(bb, ob));
                bb = fminf(bb, ob);
            }
            best[rt][r] = bb; best2[rt][r] = b2;
        }

    // ---- per-row result: flags into LDS list (LDS atomics only) ----
    if (l15 == 0) {
        #pragma unroll
        for (int rt = 0; rt < 2; ++rt)
            #pragma unroll
            for (int r = 0; r < 4; ++r) {
                unsigned ub = __float_as_uint(best[rt][r]);
                int k = (int)(ub & 1023u);
                float sb  = __uint_as_float(ub & 0xFFFFFC00u);
                float sb2 = __uint_as_float(__float_as_uint(best2[rt][r]) & 0xFFFFFC00u);
                int rowl = rowbase + rt * 16 + quad * 4 + r;
                int flag = 0;
                if (sb2 - sb < EPS) {
                    int p = atomicAdd(&blkcnt, 1);   // LDS atomic, per-CU fast
                    blkrows[p] = rowl; flag = 1;
                }
                kidx[rowl] = k | (flag << 15);
            }
    }
    __syncthreads();
    // ---- ONE global atomic per block reserves the slot range ----
    if (t == 0) blkbase = (blkcnt > 0) ? atomicAdd(counter, blkcnt) : 0;
    __syncthreads();
    if (t < blkcnt) {
        const int rowl = blkrows[t];
        const int slot = blkbase + t;
        if (slot < cap) worklist[slot] = n0 + rowl;
        else            kidx[rowl] &= 0x7FFF;   // overflow: un-flag, epilogue handles
    }
    __syncthreads();

    // ---- epilogue: row = t&127, dgrp = t>>7 covers 32 d; coalesced stores ----
    float lsum = 0.f;
    {
        const int row  = t & 127;
        const int d0   = (t >> 7) * 32;
        const int ki   = kidx[row];
        const int k    = ki & 1023;
        const int flag = (ki >> 15) & 1;
        if (!flag) {
            const float4* cbr = (const float4*)(cb + k * DIM + d0);
            const short8* zhr = (const short8*)&zh[row * PITCH + d0];
            const short8* zlr = (const short8*)&zl[row * PITCH + d0];
            float* op = out + (size_t)b * DHW + (size_t)d0 * HW + hw0 + row;
            #pragma unroll
            for (int g = 0; g < 4; ++g) {
                short8 hh = zhr[g];
                short8 ll = zlr[g];
                float4 e0 = cbr[2 * g];
                float4 e1 = cbr[2 * g + 1];
                const float ev[8] = { e0.x, e0.y, e0.z, e0.w, e1.x, e1.y, e1.z, e1.w };
                #pragma unroll
                for (int j = 0; j < 8; ++j) {
                    float zv = -0.5f * (bf16_to_f32((unsigned short)hh[j]) +
                                        bf16_to_f32((unsigned short)ll[j]));
                    op[(size_t)(g * 8 + j) * HW] = ev[j];
                    float df = ev[j] - zv;
                    lsum = fmaf(df, df, lsum);
                }
            }
        }
    }
    #pragma unroll
    for (int off = 32; off > 0; off >>= 1) lsum += __shfl_down(lsum, off, 64);
    if (lane == 0) wsum[wave] = lsum;
    __syncthreads();
    if (t == 0)
        atomicAdd(loss_acc, (double)((wsum[0] + wsum[1]) + (wsum[2] + wsum[3])));
}

// Transpose cb -> cbT[d][k] into the (now dead) ehg/elg region. Runs after
// vq_main on the same stream, so stream order guarantees ehg/elg reads are
// done. block = one d value; writes coalesced along k.
__global__ __launch_bounds__(256) void vq_transpose(
    const float* __restrict__ cb, float* __restrict__ cbT)
{
    const int d = blockIdx.x;
    const int t = threadIdx.x;
    #pragma unroll
    for (int j = 0; j < 4; ++j) {
        const int k = t + j * 256;
        cbT[(size_t)d * KCODE + k] = cb[(size_t)k * DIM + d];
    }
}

// Rescue v5: ONE WAVE PER FLAGGED VECTOR. No codebook LDS, no barriers in the
// work loop -- the barrier-phased staged structure was the schedule-invariant
// ~90 us floor (R0/R1/R5/R6: three internal reorganizations, same wall time).
// Codebook read directly from L2 via the transposed copy cbT[d][k]: lane owns
// codes j*256+4*lane..+3, so a wave's float4 loads at fixed d are 64x16B
// contiguous = perfectly coalesced 1KB/instruction. z broadcast from a
// per-wave LDS row (uniform address, conflict-free, intra-wave -> no barrier).
// ||c||^2 in f64 inline alongside the dot. Tie-break identical to prior
// versions (ascending k in-lane strict <, min-k cross-lane merge). Loss:
// per-wave register accumulation -> one f64 atomic per block.
__global__ __launch_bounds__(512) void vq_rescue(
    const float* __restrict__ z, const float* __restrict__ cb,
    const float* __restrict__ cbT, float* __restrict__ out,
    double* __restrict__ loss_acc,
    const int* __restrict__ counter, const int* __restrict__ worklist, int cap,
    int* __restrict__ done, float* __restrict__ loss_out)
{
    __shared__ float  zsh[8][DIM];   // per-wave z row
    __shared__ double dsum[8];

    int count = *counter; if (count > cap) count = cap;
    const int t    = threadIdx.x;
    const int wave = t >> 6;         // 0..7
    const int lane = t & 63;

    const float4* cbT4 = (const float4*)cbT;
    double lloss = 0.0;

    for (int i = blockIdx.x * 8 + wave; i < count; i += gridDim.x * 8) {
        const int n  = worklist[i];
        const int bb = n >> 12, hw = n & 4095;

        const float zval = z[(size_t)bb * DHW + (size_t)lane * HW + hw];
        zsh[wave][lane] = zval;
        double zn = (double)zval * (double)zval;
        #pragma unroll
        for (int m = 1; m <= 32; m <<= 1) zn += __shfl_xor(zn, m, 64);

        double bestd = 1.0e300; int bestk = 0;
        const float* zr = zsh[wave];

        #pragma unroll
        for (int j = 0; j < 4; ++j) {
            double dq0 = 0.0, dq1 = 0.0, dq2 = 0.0, dq3 = 0.0;
            double nq0 = 0.0, nq1 = 0.0, nq2 = 0.0, nq3 = 0.0;
            const float4* cp = cbT4 + (size_t)j * 64 + lane;
            #pragma unroll
            for (int d = 0; d < DIM; ++d) {
                const float4 c = cp[(size_t)d * 256];    // coalesced 1KB/wave
                const double zd = (double)zr[d];         // LDS uniform broadcast
                dq0 = fma((double)c.x, zd, dq0);
                dq1 = fma((double)c.y, zd, dq1);
                dq2 = fma((double)c.z, zd, dq2);
                dq3 = fma((double)c.w, zd, dq3);
                nq0 = fma((double)c.x, (double)c.x, nq0);
                nq1 = fma((double)c.y, (double)c.y, nq1);
                nq2 = fma((double)c.z, (double)c.z, nq2);
                nq3 = fma((double)c.w, (double)c.w, nq3);
            }
            const int k0 = j * 256 + lane * 4;
            double d2;
            d2 = fma(-2.0, dq0, nq0); if (d2 < bestd) { bestd = d2; bestk = k0;     }
            d2 = fma(-2.0, dq1, nq1); if (d2 < bestd) { bestd = d2; bestk = k0 + 1; }
            d2 = fma(-2.0, dq2, nq2); if (d2 < bestd) { bestd = d2; bestk = k0 + 2; }
            d2 = fma(-2.0, dq3, nq3); if (d2 < bestd) { bestd = d2; bestk = k0 + 3; }
        }

        // cross-lane merge: strict min, ties -> lowest k
        #pragma unroll
        for (int m = 1; m <= 32; m <<= 1) {
            double od = __shfl_xor(bestd, m, 64);
            int    ok = __shfl_xor(bestk, m, 64);
            if (od < bestd || (od == bestd && ok < bestk)) { bestd = od; bestk = ok; }
        }

        out[(size_t)bb * DHW + (size_t)lane * HW + hw] = cb[bestk * DIM + lane];
        if (lane == 0) lloss += bestd + zn;
    }

    if (lane == 0) dsum[wave] = lloss;
    __syncthreads();
    if (t == 0) {
        double s = ((dsum[0] + dsum[1]) + (dsum[2] + dsum[3]))
                 + ((dsum[4] + dsum[5]) + (dsum[6] + dsum[7]));
        if (s != 0.0) atomicAdd(loss_acc, s);
    }

    __threadfence();
    __shared__ int ticket_s;
    if (t == 0) ticket_s = atomicAdd(done, 1);
    __syncthreads();
    if (t == 0 && ticket_s == (int)gridDim.x - 1) {
        double total = atomicAdd(loss_acc, 0.0);
        *loss_out = (float)(1.25 * total * (1.0 / (double)((long)N_VEC * DIM)));
    }
}

extern "C" void kernel_launch(void* const* d_in, const int* in_sizes, int n_in,
                              void* d_out, int out_size, void* d_ws, size_t ws_size,
                              hipStream_t stream) {
    const float* z  = (const float*)d_in[0];
    const float* cb = (const float*)d_in[1];
    float* out      = (float*)d_out;
    char*  ws       = (char*)d_ws;

    double* loss_acc = (double*)ws;
    int*    counter  = (int*)(ws + 8);
    int*    done     = (int*)(ws + 12);
    float*  norms    = (float*)(ws + 64);
    short*  ehg      = (short*)(ws + 8192);
    short*  elg      = (short*)(ws + 139264);
    int*    worklist = (int*)(ws + 270336);
    float*  cbT      = (float*)(ws + 8192);   // reuses dead ehg/elg after main

    int cap = WLCAP;
    long avail = ((long)ws_size - 270336) / 4;
    if (avail < cap) cap = (avail > 0) ? (int)avail : 0;

    vq_prep<<<dim3(KCODE / 16), dim3(256), 0, stream>>>(
        cb, norms, ehg, elg, loss_acc, counter, done);
    vq_main<<<dim3(N_VEC / BLK_ROWS), dim3(256), 0, stream>>>(
        z, cb, norms, ehg, elg, out, loss_acc, counter, worklist, cap);
    vq_transpose<<<dim3(DIM), dim3(256), 0, stream>>>(cb, cbT);
    vq_rescue<<<dim3(512), dim3(512), 0, stream>>>(
        z, cb, cbT, out, loss_acc, counter, worklist, cap, done, out + (out_size - 1));
}

// Round 9
// 1513.256 us; speedup vs baseline: 1.5471x; 1.5471x over previous
//
#include <hip/hip_runtime.h>

#define N_VEC 131072   // B*H*W
#define DIM   64
#define KCODE 1024
#define HW    4096
#define DHW   262144
#define EPS   0.125f   // near-tie margin (validated r4-r8)
#define WLCAP 8192     // count ~3700 observed; 2.2x headroom
#define BLK_ROWS 128   // rows per block; 4 waves x 32 rows
#define PITCH 72       // shorts per LDS row (144 B)
#define BCHUNK 64      // main: codes per LDS-staged codebook chunk
#define NBCHUNK 16

typedef short short8 __attribute__((ext_vector_type(8)));
typedef float f32x4  __attribute__((ext_vector_type(4)));

// ws layout (bytes) -- proven 401408 footprint:
//   0      : double loss accumulator
//   8      : int flagged counter
//   12     : int done-ticket counter
//   64     : norms f32[1024]
//   8192   : eh  bf16-bits short[65536]   } dead after vq_main; reused as
//   139264 : el  bf16-bits short[65536]   } partials u64[8192][4] (256 KB exact)
//   270336 : worklist int[WLCAP]          (8192*4 = 32 KB, ends 303104)

__device__ __forceinline__ unsigned short f32_to_bf16_rne(float x) {
    unsigned u = __float_as_uint(x);
    u += 0x7FFFu + ((u >> 16) & 1u);
    return (unsigned short)(u >> 16);
}
__device__ __forceinline__ float bf16_to_f32(unsigned short h) {
    return __uint_as_float((unsigned)h << 16);
}

__global__ __launch_bounds__(256) void vq_prep(
    const float* __restrict__ cb, float* __restrict__ norms,
    short* __restrict__ ehg, short* __restrict__ elg,
    double* __restrict__ loss_acc, int* __restrict__ counter,
    int* __restrict__ done)
{
    const int t = threadIdx.x;
    if (blockIdx.x == 0 && t == 0) { *loss_acc = 0.0; *counter = 0; *done = 0; }

    const int k    = blockIdx.x * 16 + (t >> 4);
    const int part = t & 15;
    const float4 v = *(const float4*)(cb + k * DIM + part * 4);

    float s = 0.f;
    s = fmaf(v.x, v.x, s); s = fmaf(v.y, v.y, s);
    s = fmaf(v.z, v.z, s); s = fmaf(v.w, v.w, s);
    #pragma unroll
    for (int m = 1; m <= 8; m <<= 1) s += __shfl_xor(s, m, 64);
    if (part == 0) norms[k] = s;

    short h[4], l[4];
    const float vv[4] = { v.x, v.y, v.z, v.w };
    #pragma unroll
    for (int j = 0; j < 4; ++j) {
        unsigned short hh = f32_to_bf16_rne(vv[j]);
        unsigned short ll = f32_to_bf16_rne(vv[j] - bf16_to_f32(hh));
        h[j] = (short)hh; l[j] = (short)ll;
    }
    *(short4*)(ehg + k * DIM + part * 4) = make_short4(h[0], h[1], h[2], h[3]);
    *(short4*)(elg + k * DIM + part * 4) = make_short4(l[0], l[1], l[2], l[3]);
}

// Main v6 (unchanged from R5/R6): LDS-staged B double-buffered, per-block LDS
// aggregation of worklist slots -> ONE global atomicAdd per block.
__global__ __launch_bounds__(256, 2) void vq_main(
    const float* __restrict__ z, const float* __restrict__ cb,
    const float* __restrict__ norms, const short* __restrict__ ehg,
    const short* __restrict__ elg, float* __restrict__ out,
    double* __restrict__ loss_acc, int* __restrict__ counter,
    int* __restrict__ worklist, int cap)
{
    __shared__ short  zh[BLK_ROWS * PITCH];   // hi(-2z) bf16 bits, [row=hw][d]
    __shared__ short  zl[BLK_ROWS * PITCH];
    __shared__ short  ebh0[BCHUNK * PITCH];   // codebook chunk hi, double-buffered
    __shared__ short  ebh1[BCHUNK * PITCH];
    __shared__ short  ebl0[BCHUNK * PITCH];
    __shared__ short  ebl1[BCHUNK * PITCH];
    __shared__ float  nsh[KCODE];             // norms, block-resident
    __shared__ int    kidx[BLK_ROWS];
    __shared__ float  wsum[4];
    __shared__ int    blkrows[BLK_ROWS];      // flagged row-local ids
    __shared__ int    blkcnt;
    __shared__ int    blkbase;

    const int t   = threadIdx.x;              // 0..255
    const int n0  = blockIdx.x * BLK_ROWS;
    const int b   = n0 >> 12;
    const int hw0 = n0 & 4095;

    const int lane = t & 63;
    const int wave = t >> 6;                  // 0..3
    const int l15  = lane & 15;
    const int quad = lane >> 4;
    const int rowbase = wave * 32;            // 2 row-tiles per wave

    if (t == 0) blkcnt = 0;

    // ---- stage z -> LDS (8 float4/thread, register transpose, b128 writes) ----
    {
        const int hwl   = (t & 31) * 4;       // 4 consecutive rows
        const int dbase = (t >> 5) * 8;       // 8 consecutive d
        float4 v[8];
        #pragma unroll
        for (int p = 0; p < 8; ++p)
            v[p] = *(const float4*)(z + (size_t)b * DHW + (size_t)(dbase + p) * HW + hw0 + hwl);
        #pragma unroll
        for (int c = 0; c < 4; ++c) {
            short8 hi, lo;
            #pragma unroll
            for (int p = 0; p < 8; ++p) {
                const float* vp = (const float*)&v[p];
                float f = -2.0f * vp[c];
                unsigned short hh = f32_to_bf16_rne(f);
                unsigned short ll = f32_to_bf16_rne(f - bf16_to_f32(hh));
                hi[p] = (short)hh; lo[p] = (short)ll;
            }
            *(short8*)&zh[(hwl + c) * PITCH + dbase] = hi;
            *(short8*)&zl[(hwl + c) * PITCH + dbase] = lo;
        }
    }

    // ---- stage norms -> LDS ----
    #pragma unroll
    for (int j = 0; j < 4; ++j) nsh[t + j * 256] = norms[t + j * 256];

    // ---- B-staging prologue: thread owns 32 B hi + 32 B lo per chunk ----
    const int cc = t >> 2;                    // code within chunk (0..63)
    const int pp = (t & 3) * 16;              // short offset within code row
    short8 pf0[4], pf1[4];                    // [0..1]=hi, [2..3]=lo
    #pragma unroll
    for (int j = 0; j < 2; ++j) {
        pf0[j]     = *(const short8*)(ehg + (size_t)cc * DIM + pp + j * 8);
        pf0[2 + j] = *(const short8*)(elg + (size_t)cc * DIM + pp + j * 8);
        pf1[j]     = *(const short8*)(ehg + (size_t)(BCHUNK + cc) * DIM + pp + j * 8);
        pf1[2 + j] = *(const short8*)(elg + (size_t)(BCHUNK + cc) * DIM + pp + j * 8);
    }
    __syncthreads();                          // z + norms ready (prologue loads drain once)

    // ---- A-fragments (32 VGPRs, resident) ----
    short8 a_h[2][2], a_l[2][2];
    #pragma unroll
    for (int rt = 0; rt < 2; ++rt)
        #pragma unroll
        for (int kt = 0; kt < 2; ++kt) {
            const int idx = (rowbase + rt * 16 + l15) * PITCH + kt * 32 + quad * 8;
            a_h[rt][kt] = *(const short8*)&zh[idx];
            a_l[rt][kt] = *(const short8*)&zl[idx];
        }

    // ---- write chunk 0 into buf0 ----
    #pragma unroll
    for (int j = 0; j < 2; ++j) {
        *(short8*)&ebh0[cc * PITCH + pp + j * 8] = pf0[j];
        *(short8*)&ebl0[cc * PITCH + pp + j * 8] = pf0[2 + j];
    }
    __syncthreads();                          // buf0 ready

    float best[2][4], best2[2][4];
    #pragma unroll
    for (int rt = 0; rt < 2; ++rt)
        #pragma unroll
        for (int r = 0; r < 4; ++r) { best[rt][r] = 3.0e38f; best2[rt][r] = 3.0e38f; }

    // chunk body: issue ch+2 loads -> pfL; compute chunk ch from (bhR,blR);
    // write pfW (chunk ch+1) -> (bhW,blW); barrier.
    auto body = [&](int ch, const short* bhR, const short* blR,
                    short* bhW, short* blW, short8 (&pfL)[4], short8 (&pfW)[4]) {
        if (ch + 2 < NBCHUNK) {
            const size_t gb = (size_t)((ch + 2) * BCHUNK + cc) * DIM + pp;
            #pragma unroll
            for (int j = 0; j < 2; ++j) {
                pfL[j]     = *(const short8*)(ehg + gb + j * 8);
                pfL[2 + j] = *(const short8*)(elg + gb + j * 8);
            }
        }
        // hoist the 4 norm reads (they gate each MFMA chain's acc init)
        float nrm4[4];
        #pragma unroll
        for (int ct = 0; ct < 4; ++ct) nrm4[ct] = nsh[ch * BCHUNK + ct * 16 + l15];

        #pragma unroll
        for (int ct = 0; ct < 4; ++ct) {
            const int crow = ct * 16 + l15;
            short8 Bh0 = *(const short8*)&bhR[crow * PITCH + quad * 8];
            short8 Bh1 = *(const short8*)&bhR[crow * PITCH + 32 + quad * 8];
            short8 Bl0 = *(const short8*)&blR[crow * PITCH + quad * 8];
            short8 Bl1 = *(const short8*)&blR[crow * PITCH + 32 + quad * 8];
            const unsigned colbits = (unsigned)(ch * BCHUNK + crow);
            const float nrm = nrm4[ct];
            #pragma unroll
            for (int rt = 0; rt < 2; ++rt) {
                f32x4 acc = { nrm, nrm, nrm, nrm };
                acc = __builtin_amdgcn_mfma_f32_16x16x32_bf16(a_h[rt][0], Bh0, acc, 0, 0, 0);
                acc = __builtin_amdgcn_mfma_f32_16x16x32_bf16(a_h[rt][1], Bh1, acc, 0, 0, 0);
                acc = __builtin_amdgcn_mfma_f32_16x16x32_bf16(a_h[rt][0], Bl0, acc, 0, 0, 0);
                acc = __builtin_amdgcn_mfma_f32_16x16x32_bf16(a_h[rt][1], Bl1, acc, 0, 0, 0);
                acc = __builtin_amdgcn_mfma_f32_16x16x32_bf16(a_l[rt][0], Bh0, acc, 0, 0, 0);
                acc = __builtin_amdgcn_mfma_f32_16x16x32_bf16(a_l[rt][1], Bh1, acc, 0, 0, 0);
                #pragma unroll
                for (int r = 0; r < 4; ++r) {
                    float p = __uint_as_float((__float_as_uint(acc[r]) & 0xFFFFFC00u) | colbits);
                    best2[rt][r] = fminf(best2[rt][r], fmaxf(best[rt][r], p));
                    best[rt][r]  = fminf(best[rt][r], p);
                }
            }
        }
        if (ch + 1 < NBCHUNK) {
            #pragma unroll
            for (int j = 0; j < 2; ++j) {
                *(short8*)&bhW[cc * PITCH + pp + j * 8] = pfW[j];
                *(short8*)&blW[cc * PITCH + pp + j * 8] = pfW[2 + j];
            }
        }
        __syncthreads();
    };

    for (int chp = 0; chp < 8; ++chp) {
        body(2 * chp,     ebh0, ebl0, ebh1, ebl1, pf0, pf1);
        body(2 * chp + 1, ebh1, ebl1, ebh0, ebl0, pf1, pf0);
    }

    // ---- merge across 16 code-lanes; each wave has complete top-2 for its rows ----
    #pragma unroll
    for (int rt = 0; rt < 2; ++rt)
        #pragma unroll
        for (int r = 0; r < 4; ++r) {
            float bb = best[rt][r], b2 = best2[rt][r];
            #pragma unroll
            for (int m = 1; m <= 8; m <<= 1) {
                float ob  = __shfl_xor(bb, m, 64);
                float ob2 = __shfl_xor(b2, m, 64);
                b2 = fminf(fminf(b2, ob2), fmaxf(bb, ob));
                bb = fminf(bb, ob);
            }
            best[rt][r] = bb; best2[rt][r] = b2;
        }

    // ---- per-row result: flags into LDS list (LDS atomics only) ----
    if (l15 == 0) {
        #pragma unroll
        for (int rt = 0; rt < 2; ++rt)
            #pragma unroll
            for (int r = 0; r < 4; ++r) {
                unsigned ub = __float_as_uint(best[rt][r]);
                int k = (int)(ub & 1023u);
                float sb  = __uint_as_float(ub & 0xFFFFFC00u);
                float sb2 = __uint_as_float(__float_as_uint(best2[rt][r]) & 0xFFFFFC00u);
                int rowl = rowbase + rt * 16 + quad * 4 + r;
                int flag = 0;
                if (sb2 - sb < EPS) {
                    int p = atomicAdd(&blkcnt, 1);   // LDS atomic, per-CU fast
                    blkrows[p] = rowl; flag = 1;
                }
                kidx[rowl] = k | (flag << 15);
            }
    }
    __syncthreads();
    // ---- ONE global atomic per block reserves the slot range ----
    if (t == 0) blkbase = (blkcnt > 0) ? atomicAdd(counter, blkcnt) : 0;
    __syncthreads();
    if (t < blkcnt) {
        const int rowl = blkrows[t];
        const int slot = blkbase + t;
        if (slot < cap) worklist[slot] = n0 + rowl;
        else            kidx[rowl] &= 0x7FFF;   // overflow: un-flag, epilogue handles
    }
    __syncthreads();

    // ---- epilogue: row = t&127, dgrp = t>>7 covers 32 d; coalesced stores ----
    float lsum = 0.f;
    {
        const int row  = t & 127;
        const int d0   = (t >> 7) * 32;
        const int ki   = kidx[row];
        const int k    = ki & 1023;
        const int flag = (ki >> 15) & 1;
        if (!flag) {
            const float4* cbr = (const float4*)(cb + k * DIM + d0);
            const short8* zhr = (const short8*)&zh[row * PITCH + d0];
            const short8* zlr = (const short8*)&zl[row * PITCH + d0];
            float* op = out + (size_t)b * DHW + (size_t)d0 * HW + hw0 + row;
            #pragma unroll
            for (int g = 0; g < 4; ++g) {
                short8 hh = zhr[g];
                short8 ll = zlr[g];
                float4 e0 = cbr[2 * g];
                float4 e1 = cbr[2 * g + 1];
                const float ev[8] = { e0.x, e0.y, e0.z, e0.w, e1.x, e1.y, e1.z, e1.w };
                #pragma unroll
                for (int j = 0; j < 8; ++j) {
                    float zv = -0.5f * (bf16_to_f32((unsigned short)hh[j]) +
                                        bf16_to_f32((unsigned short)ll[j]));
                    op[(size_t)(g * 8 + j) * HW] = ev[j];
                    float df = ev[j] - zv;
                    lsum = fmaf(df, df, lsum);
                }
            }
        }
    }
    #pragma unroll
    for (int off = 32; off > 0; off >>= 1) lsum += __shfl_down(lsum, off, 64);
    if (lane == 0) wsum[wave] = lsum;
    __syncthreads();
    if (t == 0)
        atomicAdd(loss_acc, (double)((wsum[0] + wsum[1]) + (wsum[2] + wsum[3])));
}

// Rescue v6 part 1: (vector-group x chunk)-parallel exact scan. Block
// (vg=bid>>2, chunk=bid&3) computes f64 distances of 8 vectors (4 waves x 2)
// against 256 codes, reading rows DIRECTLY from cb (input buffer, L2-hot --
// NOT the workspace, whose re-reads were R8's 25x disaster). Zero barriers,
// no codebook LDS; serial chain ~1/4 of the old monolith. Result packed
// order-preservingly: bits(max(d2+||z||^2,0)) & ~1023 | k  (non-negative
// doubles compare as u64; low-bits k reproduces min-k tie-break; 2^-42 error
// far below f32-reference visibility). Partials land in the dead ehg/elg
// region (8192*4*8B = 256 KB exact).
__global__ __launch_bounds__(256, 4) void vq_rescue_part(
    const float* __restrict__ z, const float* __restrict__ cb,
    const int* __restrict__ counter, const int* __restrict__ worklist, int cap,
    unsigned long long* __restrict__ partials)
{
    __shared__ float zsh[8][DIM];    // per (wave,v) z row

    int count = *counter; if (count > cap) count = cap;
    const int t    = threadIdx.x;
    const int wave = t >> 6;         // 0..3
    const int lane = t & 63;
    const int chunk = blockIdx.x & 3;
    const int nvg   = (int)(gridDim.x >> 2);
    const int krow  = chunk * 256 + lane;     // + j*64

    for (int vg = (int)(blockIdx.x >> 2); vg * 8 < count; vg += nvg) {
        int    idx[2]; bool act[2]; double zn[2];
        #pragma unroll
        for (int v = 0; v < 2; ++v) {
            const int i = vg * 8 + wave * 2 + v;
            idx[v] = i; act[v] = (i < count);
            float zval = 0.f;
            if (act[v]) {
                const int n = worklist[i];
                const int bb = n >> 12, hw = n & 4095;
                zval = z[(size_t)bb * DHW + (size_t)lane * HW + hw];
            }
            zsh[wave * 2 + v][lane] = zval;
            double s = (double)zval * (double)zval;
            #pragma unroll
            for (int m = 1; m <= 32; m <<= 1) s += __shfl_xor(s, m, 64);
            zn[v] = s;
        }

        unsigned long long best0 = ~0ull, best1 = ~0ull;
        #pragma unroll
        for (int j = 0; j < 4; ++j) {
            const float* cr = cb + (size_t)(krow + j * 64) * DIM;
            double nj = 0.0, d0 = 0.0, d1 = 0.0;
            #pragma unroll
            for (int dblk = 0; dblk < 8; ++dblk) {
                const float4 c0 = *(const float4*)(cr + dblk * 8);
                const float4 c1 = *(const float4*)(cr + dblk * 8 + 4);
                const float cv[8] = { c0.x, c0.y, c0.z, c0.w, c1.x, c1.y, c1.z, c1.w };
                float zb0[8], zb1[8];
                #pragma unroll
                for (int dd = 0; dd < 8; ++dd) {
                    zb0[dd] = zsh[wave * 2 + 0][dblk * 8 + dd];
                    zb1[dd] = zsh[wave * 2 + 1][dblk * 8 + dd];
                }
                #pragma unroll
                for (int dd = 0; dd < 8; ++dd)
                    nj = fma((double)cv[dd], (double)cv[dd], nj);
                #pragma unroll
                for (int dd = 0; dd < 8; ++dd) {
                    d0 = fma((double)cv[dd], (double)zb0[dd], d0);
                    d1 = fma((double)cv[dd], (double)zb1[dd], d1);
                }
            }
            const unsigned long long gk = (unsigned long long)(krow + j * 64);
            double p0 = fmax(fma(-2.0, d0, nj) + zn[0], 0.0);
            double p1 = fmax(fma(-2.0, d1, nj) + zn[1], 0.0);
            unsigned long long q0 = ((unsigned long long)__double_as_longlong(p0) & ~1023ull) | gk;
            unsigned long long q1 = ((unsigned long long)__double_as_longlong(p1) & ~1023ull) | gk;
            if (q0 < best0) best0 = q0;
            if (q1 < best1) best1 = q1;
        }

        #pragma unroll
        for (int m = 1; m <= 32; m <<= 1) {
            unsigned long long o0 = __shfl_xor(best0, m, 64);
            unsigned long long o1 = __shfl_xor(best1, m, 64);
            if (o0 < best0) best0 = o0;
            if (o1 < best1) best1 = o1;
        }
        if (lane == 0) {
            if (act[0]) partials[(size_t)idx[0] * 4 + chunk] = best0;
            if (act[1]) partials[(size_t)idx[1] * 4 + chunk] = best1;
        }
    }
}

// Rescue v6 part 2: per flagged vector, min of the 4 chunk partials -> k;
// write the out row from cb; loss = packed value with k-bits stripped
// (= d^2+||z||^2, error ~2^-42). One f64 atomic per block; ticket finalizes.
__global__ __launch_bounds__(256) void vq_merge(
    const float* __restrict__ cb, float* __restrict__ out,
    double* __restrict__ loss_acc,
    const int* __restrict__ counter, const int* __restrict__ worklist, int cap,
    const unsigned long long* __restrict__ partials,
    int* __restrict__ done, float* __restrict__ loss_out)
{
    __shared__ double dsum[4];

    int count = *counter; if (count > cap) count = cap;
    const int t    = threadIdx.x;
    const int wave = t >> 6;
    const int lane = t & 63;

    double lloss = 0.0;
    for (int i = blockIdx.x * 4 + wave; i < count; i += gridDim.x * 4) {
        unsigned long long p0 = partials[(size_t)i * 4 + 0];
        unsigned long long p1 = partials[(size_t)i * 4 + 1];
        unsigned long long p2 = partials[(size_t)i * 4 + 2];
        unsigned long long p3 = partials[(size_t)i * 4 + 3];
        unsigned long long p = p0 < p1 ? p0 : p1;
        if (p2 < p) p = p2;
        if (p3 < p) p = p3;
        const int k = (int)(p & 1023ull);

        const int n  = worklist[i];
        const int bb = n >> 12, hw = n & 4095;
        out[(size_t)bb * DHW + (size_t)lane * HW + hw] = cb[(size_t)k * DIM + lane];
        if (lane == 0)
            lloss += __longlong_as_double((long long)(p & ~1023ull));
    }

    if (lane == 0) dsum[wave] = lloss;
    __syncthreads();
    if (t == 0) {
        double s = (dsum[0] + dsum[1]) + (dsum[2] + dsum[3]);
        if (s != 0.0) atomicAdd(loss_acc, s);
    }

    __threadfence();
    __shared__ int ticket_s;
    if (t == 0) ticket_s = atomicAdd(done, 1);
    __syncthreads();
    if (t == 0 && ticket_s == (int)gridDim.x - 1) {
        double total = atomicAdd(loss_acc, 0.0);
        *loss_out = (float)(1.25 * total * (1.0 / (double)((long)N_VEC * DIM)));
    }
}

extern "C" void kernel_launch(void* const* d_in, const int* in_sizes, int n_in,
                              void* d_out, int out_size, void* d_ws, size_t ws_size,
                              hipStream_t stream) {
    const float* z  = (const float*)d_in[0];
    const float* cb = (const float*)d_in[1];
    float* out      = (float*)d_out;
    char*  ws       = (char*)d_ws;

    double* loss_acc = (double*)ws;
    int*    counter  = (int*)(ws + 8);
    int*    done     = (int*)(ws + 12);
    float*  norms    = (float*)(ws + 64);
    short*  ehg      = (short*)(ws + 8192);
    short*  elg      = (short*)(ws + 139264);
    int*    worklist = (int*)(ws + 270336);
    unsigned long long* partials = (unsigned long long*)(ws + 8192); // dead ehg/elg

    int cap = WLCAP;
    long avail = ((long)ws_size - 270336) / 4;
    if (avail < cap) cap = (avail > 0) ? (int)avail : 0;

    vq_prep<<<dim3(KCODE / 16), dim3(256), 0, stream>>>(
        cb, norms, ehg, elg, loss_acc, counter, done);
    vq_main<<<dim3(N_VEC / BLK_ROWS), dim3(256), 0, stream>>>(
        z, cb, norms, ehg, elg, out, loss_acc, counter, worklist, cap);
    vq_rescue_part<<<dim3(2048), dim3(256), 0, stream>>>(
        z, cb, counter, worklist, cap, partials);
    vq_merge<<<dim3(512), dim3(256), 0, stream>>>(
        cb, out, loss_acc, counter, worklist, cap, partials, done, out + (out_size - 1));
}

// Round 10
// 599.059 us; speedup vs baseline: 3.9080x; 2.5261x over previous
//
#include <hip/hip_runtime.h>

#define N_VEC 131072   // B*H*W
#define DIM   64
#define KCODE 1024
#define HW    4096
#define DHW   262144
#define EPS   0.125f   // near-tie margin (validated r4-r8)
#define WLCAP 8192     // count ~3700 observed; 2.2x headroom
#define BLK_ROWS 128   // rows per block; 4 waves x 32 rows
#define PITCH 72       // shorts per LDS row (144 B)
#define BCHUNK 64      // main: codes per LDS-staged codebook chunk
#define NBCHUNK 16

typedef short short8 __attribute__((ext_vector_type(8)));
typedef float f32x4  __attribute__((ext_vector_type(4)));

// ws layout (bytes) -- proven 401408 footprint:
//   0      : double loss accumulator
//   8      : int flagged counter
//   12     : int done-ticket counter
//   64     : norms f32[1024]
//   8192   : eh  bf16-bits short[65536]
//   139264 : el  bf16-bits short[65536]
//   270336 : worklist int[WLCAP]          (ends 303104)

__device__ __forceinline__ unsigned short f32_to_bf16_rne(float x) {
    unsigned u = __float_as_uint(x);
    u += 0x7FFFu + ((u >> 16) & 1u);
    return (unsigned short)(u >> 16);
}
__device__ __forceinline__ float bf16_to_f32(unsigned short h) {
    return __uint_as_float((unsigned)h << 16);
}

__global__ __launch_bounds__(256) void vq_prep(
    const float* __restrict__ cb, float* __restrict__ norms,
    short* __restrict__ ehg, short* __restrict__ elg,
    double* __restrict__ loss_acc, int* __restrict__ counter,
    int* __restrict__ done)
{
    const int t = threadIdx.x;
    if (blockIdx.x == 0 && t == 0) { *loss_acc = 0.0; *counter = 0; *done = 0; }

    const int k    = blockIdx.x * 16 + (t >> 4);
    const int part = t & 15;
    const float4 v = *(const float4*)(cb + k * DIM + part * 4);

    float s = 0.f;
    s = fmaf(v.x, v.x, s); s = fmaf(v.y, v.y, s);
    s = fmaf(v.z, v.z, s); s = fmaf(v.w, v.w, s);
    #pragma unroll
    for (int m = 1; m <= 8; m <<= 1) s += __shfl_xor(s, m, 64);
    if (part == 0) norms[k] = s;

    short h[4], l[4];
    const float vv[4] = { v.x, v.y, v.z, v.w };
    #pragma unroll
    for (int j = 0; j < 4; ++j) {
        unsigned short hh = f32_to_bf16_rne(vv[j]);
        unsigned short ll = f32_to_bf16_rne(vv[j] - bf16_to_f32(hh));
        h[j] = (short)hh; l[j] = (short)ll;
    }
    *(short4*)(ehg + k * DIM + part * 4) = make_short4(h[0], h[1], h[2], h[3]);
    *(short4*)(elg + k * DIM + part * 4) = make_short4(l[0], l[1], l[2], l[3]);
}

// Main v6 (unchanged from R5/R6): LDS-staged B double-buffered, per-block LDS
// aggregation of worklist slots -> ONE global atomicAdd per block.
__global__ __launch_bounds__(256, 2) void vq_main(
    const float* __restrict__ z, const float* __restrict__ cb,
    const float* __restrict__ norms, const short* __restrict__ ehg,
    const short* __restrict__ elg, float* __restrict__ out,
    double* __restrict__ loss_acc, int* __restrict__ counter,
    int* __restrict__ worklist, int cap)
{
    __shared__ short  zh[BLK_ROWS * PITCH];   // hi(-2z) bf16 bits, [row=hw][d]
    __shared__ short  zl[BLK_ROWS * PITCH];
    __shared__ short  ebh0[BCHUNK * PITCH];   // codebook chunk hi, double-buffered
    __shared__ short  ebh1[BCHUNK * PITCH];
    __shared__ short  ebl0[BCHUNK * PITCH];
    __shared__ short  ebl1[BCHUNK * PITCH];
    __shared__ float  nsh[KCODE];             // norms, block-resident
    __shared__ int    kidx[BLK_ROWS];
    __shared__ float  wsum[4];
    __shared__ int    blkrows[BLK_ROWS];      // flagged row-local ids
    __shared__ int    blkcnt;
    __shared__ int    blkbase;

    const int t   = threadIdx.x;              // 0..255
    const int n0  = blockIdx.x * BLK_ROWS;
    const int b   = n0 >> 12;
    const int hw0 = n0 & 4095;

    const int lane = t & 63;
    const int wave = t >> 6;                  // 0..3
    const int l15  = lane & 15;
    const int quad = lane >> 4;
    const int rowbase = wave * 32;            // 2 row-tiles per wave

    if (t == 0) blkcnt = 0;

    // ---- stage z -> LDS (8 float4/thread, register transpose, b128 writes) ----
    {
        const int hwl   = (t & 31) * 4;       // 4 consecutive rows
        const int dbase = (t >> 5) * 8;       // 8 consecutive d
        float4 v[8];
        #pragma unroll
        for (int p = 0; p < 8; ++p)
            v[p] = *(const float4*)(z + (size_t)b * DHW + (size_t)(dbase + p) * HW + hw0 + hwl);
        #pragma unroll
        for (int c = 0; c < 4; ++c) {
            short8 hi, lo;
            #pragma unroll
            for (int p = 0; p < 8; ++p) {
                const float* vp = (const float*)&v[p];
                float f = -2.0f * vp[c];
                unsigned short hh = f32_to_bf16_rne(f);
                unsigned short ll = f32_to_bf16_rne(f - bf16_to_f32(hh));
                hi[p] = (short)hh; lo[p] = (short)ll;
            }
            *(short8*)&zh[(hwl + c) * PITCH + dbase] = hi;
            *(short8*)&zl[(hwl + c) * PITCH + dbase] = lo;
        }
    }

    // ---- stage norms -> LDS ----
    #pragma unroll
    for (int j = 0; j < 4; ++j) nsh[t + j * 256] = norms[t + j * 256];

    // ---- B-staging prologue: thread owns 32 B hi + 32 B lo per chunk ----
    const int cc = t >> 2;                    // code within chunk (0..63)
    const int pp = (t & 3) * 16;              // short offset within code row
    short8 pf0[4], pf1[4];                    // [0..1]=hi, [2..3]=lo
    #pragma unroll
    for (int j = 0; j < 2; ++j) {
        pf0[j]     = *(const short8*)(ehg + (size_t)cc * DIM + pp + j * 8);
        pf0[2 + j] = *(const short8*)(elg + (size_t)cc * DIM + pp + j * 8);
        pf1[j]     = *(const short8*)(ehg + (size_t)(BCHUNK + cc) * DIM + pp + j * 8);
        pf1[2 + j] = *(const short8*)(elg + (size_t)(BCHUNK + cc) * DIM + pp + j * 8);
    }
    __syncthreads();                          // z + norms ready (prologue loads drain once)

    // ---- A-fragments (32 VGPRs, resident) ----
    short8 a_h[2][2], a_l[2][2];
    #pragma unroll
    for (int rt = 0; rt < 2; ++rt)
        #pragma unroll
        for (int kt = 0; kt < 2; ++kt) {
            const int idx = (rowbase + rt * 16 + l15) * PITCH + kt * 32 + quad * 8;
            a_h[rt][kt] = *(const short8*)&zh[idx];
            a_l[rt][kt] = *(const short8*)&zl[idx];
        }

    // ---- write chunk 0 into buf0 ----
    #pragma unroll
    for (int j = 0; j < 2; ++j) {
        *(short8*)&ebh0[cc * PITCH + pp + j * 8] = pf0[j];
        *(short8*)&ebl0[cc * PITCH + pp + j * 8] = pf0[2 + j];
    }
    __syncthreads();                          // buf0 ready

    float best[2][4], best2[2][4];
    #pragma unroll
    for (int rt = 0; rt < 2; ++rt)
        #pragma unroll
        for (int r = 0; r < 4; ++r) { best[rt][r] = 3.0e38f; best2[rt][r] = 3.0e38f; }

    // chunk body: issue ch+2 loads -> pfL; compute chunk ch from (bhR,blR);
    // write pfW (chunk ch+1) -> (bhW,blW); barrier.
    auto body = [&](int ch, const short* bhR, const short* blR,
                    short* bhW, short* blW, short8 (&pfL)[4], short8 (&pfW)[4]) {
        if (ch + 2 < NBCHUNK) {
            const size_t gb = (size_t)((ch + 2) * BCHUNK + cc) * DIM + pp;
            #pragma unroll
            for (int j = 0; j < 2; ++j) {
                pfL[j]     = *(const short8*)(ehg + gb + j * 8);
                pfL[2 + j] = *(const short8*)(elg + gb + j * 8);
            }
        }
        // hoist the 4 norm reads (they gate each MFMA chain's acc init)
        float nrm4[4];
        #pragma unroll
        for (int ct = 0; ct < 4; ++ct) nrm4[ct] = nsh[ch * BCHUNK + ct * 16 + l15];

        #pragma unroll
        for (int ct = 0; ct < 4; ++ct) {
            const int crow = ct * 16 + l15;
            short8 Bh0 = *(const short8*)&bhR[crow * PITCH + quad * 8];
            short8 Bh1 = *(const short8*)&bhR[crow * PITCH + 32 + quad * 8];
            short8 Bl0 = *(const short8*)&blR[crow * PITCH + quad * 8];
            short8 Bl1 = *(const short8*)&blR[crow * PITCH + 32 + quad * 8];
            const unsigned colbits = (unsigned)(ch * BCHUNK + crow);
            const float nrm = nrm4[ct];
            #pragma unroll
            for (int rt = 0; rt < 2; ++rt) {
                f32x4 acc = { nrm, nrm, nrm, nrm };
                acc = __builtin_amdgcn_mfma_f32_16x16x32_bf16(a_h[rt][0], Bh0, acc, 0, 0, 0);
                acc = __builtin_amdgcn_mfma_f32_16x16x32_bf16(a_h[rt][1], Bh1, acc, 0, 0, 0);
                acc = __builtin_amdgcn_mfma_f32_16x16x32_bf16(a_h[rt][0], Bl0, acc, 0, 0, 0);
                acc = __builtin_amdgcn_mfma_f32_16x16x32_bf16(a_h[rt][1], Bl1, acc, 0, 0, 0);
                acc = __builtin_amdgcn_mfma_f32_16x16x32_bf16(a_l[rt][0], Bh0, acc, 0, 0, 0);
                acc = __builtin_amdgcn_mfma_f32_16x16x32_bf16(a_l[rt][1], Bh1, acc, 0, 0, 0);
                #pragma unroll
                for (int r = 0; r < 4; ++r) {
                    float p = __uint_as_float((__float_as_uint(acc[r]) & 0xFFFFFC00u) | colbits);
                    best2[rt][r] = fminf(best2[rt][r], fmaxf(best[rt][r], p));
                    best[rt][r]  = fminf(best[rt][r], p);
                }
            }
        }
        if (ch + 1 < NBCHUNK) {
            #pragma unroll
            for (int j = 0; j < 2; ++j) {
                *(short8*)&bhW[cc * PITCH + pp + j * 8] = pfW[j];
                *(short8*)&blW[cc * PITCH + pp + j * 8] = pfW[2 + j];
            }
        }
        __syncthreads();
    };

    for (int chp = 0; chp < 8; ++chp) {
        body(2 * chp,     ebh0, ebl0, ebh1, ebl1, pf0, pf1);
        body(2 * chp + 1, ebh1, ebl1, ebh0, ebl0, pf1, pf0);
    }

    // ---- merge across 16 code-lanes; each wave has complete top-2 for its rows ----
    #pragma unroll
    for (int rt = 0; rt < 2; ++rt)
        #pragma unroll
        for (int r = 0; r < 4; ++r) {
            float bb = best[rt][r], b2 = best2[rt][r];
            #pragma unroll
            for (int m = 1; m <= 8; m <<= 1) {
                float ob  = __shfl_xor(bb, m, 64);
                float ob2 = __shfl_xor(b2, m, 64);
                b2 = fminf(fminf(b2, ob2), fmaxf(bb, ob));
                bb = fminf(bb, ob);
            }
            best[rt][r] = bb; best2[rt][r] = b2;
        }

    // ---- per-row result: flags into LDS list (LDS atomics only) ----
    if (l15 == 0) {
        #pragma unroll
        for (int rt = 0; rt < 2; ++rt)
            #pragma unroll
            for (int r = 0; r < 4; ++r) {
                unsigned ub = __float_as_uint(best[rt][r]);
                int k = (int)(ub & 1023u);
                float sb  = __uint_as_float(ub & 0xFFFFFC00u);
                float sb2 = __uint_as_float(__float_as_uint(best2[rt][r]) & 0xFFFFFC00u);
                int rowl = rowbase + rt * 16 + quad * 4 + r;
                int flag = 0;
                if (sb2 - sb < EPS) {
                    int p = atomicAdd(&blkcnt, 1);   // LDS atomic, per-CU fast
                    blkrows[p] = rowl; flag = 1;
                }
                kidx[rowl] = k | (flag << 15);
            }
    }
    __syncthreads();
    // ---- ONE global atomic per block reserves the slot range ----
    if (t == 0) blkbase = (blkcnt > 0) ? atomicAdd(counter, blkcnt) : 0;
    __syncthreads();
    if (t < blkcnt) {
        const int rowl = blkrows[t];
        const int slot = blkbase + t;
        if (slot < cap) worklist[slot] = n0 + rowl;
        else            kidx[rowl] &= 0x7FFF;   // overflow: un-flag, epilogue handles
    }
    __syncthreads();

    // ---- epilogue: row = t&127, dgrp = t>>7 covers 32 d; coalesced stores ----
    float lsum = 0.f;
    {
        const int row  = t & 127;
        const int d0   = (t >> 7) * 32;
        const int ki   = kidx[row];
        const int k    = ki & 1023;
        const int flag = (ki >> 15) & 1;
        if (!flag) {
            const float4* cbr = (const float4*)(cb + k * DIM + d0);
            const short8* zhr = (const short8*)&zh[row * PITCH + d0];
            const short8* zlr = (const short8*)&zl[row * PITCH + d0];
            float* op = out + (size_t)b * DHW + (size_t)d0 * HW + hw0 + row;
            #pragma unroll
            for (int g = 0; g < 4; ++g) {
                short8 hh = zhr[g];
                short8 ll = zlr[g];
                float4 e0 = cbr[2 * g];
                float4 e1 = cbr[2 * g + 1];
                const float ev[8] = { e0.x, e0.y, e0.z, e0.w, e1.x, e1.y, e1.z, e1.w };
                #pragma unroll
                for (int j = 0; j < 8; ++j) {
                    float zv = -0.5f * (bf16_to_f32((unsigned short)hh[j]) +
                                        bf16_to_f32((unsigned short)ll[j]));
                    op[(size_t)(g * 8 + j) * HW] = ev[j];
                    float df = ev[j] - zv;
                    lsum = fmaf(df, df, lsum);
                }
            }
        }
    }
    #pragma unroll
    for (int off = 32; off > 0; off >>= 1) lsum += __shfl_down(lsum, off, 64);
    if (lane == 0) wsum[wave] = lsum;
    __syncthreads();
    if (t == 0)
        atomicAdd(loss_acc, (double)((wsum[0] + wsum[1]) + (wsum[2] + wsum[3])));
}

// Rescue v7: one vector per block-iteration, wave w scans chunk w (256 codes).
// Per lane: 4 code rows SEQUENTIALLY -- live state is {best u64, nj, dt,
// float4 c} (~20 VGPRs, no arrays, nothing spillable; R9's 1.47 GB WRITE_SIZE
// was scratch spill from per-thread arrays). cb rows read directly from the
// input buffer (L2-resident; ~947 MB aggregate at L2 BW ~ 27 us floor).
// z staged once per vector into 256 B LDS by wave 0. Packed-u64 order-
// preserving min (bits(max(d2+zn,0)) & ~1023 | k) reproduces min-k tie-break;
// error 2^-42, invisible at f32. Loss: block-accumulated -> ONE f64 atomic per
// block (512 total, proven); ticket finalizes.
__global__ __launch_bounds__(256) void vq_rescue(
    const float* __restrict__ z, const float* __restrict__ cb,
    float* __restrict__ out, double* __restrict__ loss_acc,
    const int* __restrict__ counter, const int* __restrict__ worklist, int cap,
    int* __restrict__ done, float* __restrict__ loss_out)
{
    __shared__ float zsh[DIM];                 // one z row
    __shared__ unsigned long long pls[4];      // per-wave packed partials

    int count = *counter; if (count > cap) count = cap;
    const int t    = threadIdx.x;
    const int wave = t >> 6;
    const int lane = t & 63;

    double lloss = 0.0;                        // wave0/lane0 accumulator

    for (int i = blockIdx.x; i < count; i += gridDim.x) {
        const int n  = worklist[i];
        const int bb = n >> 12, hw = n & 4095;
        if (wave == 0)
            zsh[lane] = z[(size_t)bb * DHW + (size_t)lane * HW + hw];
        __syncthreads();                       // z row visible

        // per-wave ||z||^2 (uniform value, recomputed cheaply per wave)
        const float zl = zsh[lane];
        double zn = (double)zl * (double)zl;
        #pragma unroll
        for (int m = 1; m <= 32; m <<= 1) zn += __shfl_xor(zn, m, 64);

        unsigned long long best = ~0ull;
        #pragma unroll
        for (int r = 0; r < 4; ++r) {
            const int k = wave * 256 + r * 64 + lane;
            const float4* cr = (const float4*)(cb + (size_t)k * DIM);
            double nj = 0.0, dt = 0.0;
            #pragma unroll
            for (int q = 0; q < 16; ++q) {
                const float4 c  = cr[q];
                const float4 zv = *(const float4*)&zsh[q * 4];
                nj = fma((double)c.x, (double)c.x, nj);
                nj = fma((double)c.y, (double)c.y, nj);
                nj = fma((double)c.z, (double)c.z, nj);
                nj = fma((double)c.w, (double)c.w, nj);
                dt = fma((double)c.x, (double)zv.x, dt);
                dt = fma((double)c.y, (double)zv.y, dt);
                dt = fma((double)c.z, (double)zv.z, dt);
                dt = fma((double)c.w, (double)zv.w, dt);
            }
            const double p = fmax(fma(-2.0, dt, nj) + zn, 0.0);
            const unsigned long long q64 =
                ((unsigned long long)__double_as_longlong(p) & ~1023ull)
                | (unsigned long long)k;
            if (q64 < best) best = q64;
        }

        #pragma unroll
        for (int m = 1; m <= 32; m <<= 1) {
            unsigned long long o = __shfl_xor(best, m, 64);
            if (o < best) best = o;
        }
        if (lane == 0) pls[wave] = best;
        __syncthreads();                       // partials visible

        if (wave == 0) {
            unsigned long long p0 = pls[0], p1 = pls[1];
            unsigned long long p2 = pls[2], p3 = pls[3];
            unsigned long long p = p0 < p1 ? p0 : p1;
            if (p2 < p) p = p2;
            if (p3 < p) p = p3;
            const int bk = (int)(p & 1023ull);
            out[(size_t)bb * DHW + (size_t)lane * HW + hw] = cb[(size_t)bk * DIM + lane];
            if (lane == 0)
                lloss += __longlong_as_double((long long)(p & ~1023ull));
        }
    }

    if (wave == 0 && lane == 0 && lloss != 0.0) atomicAdd(loss_acc, lloss);

    __threadfence();
    __shared__ int ticket_s;
    if (t == 0) ticket_s = atomicAdd(done, 1);
    __syncthreads();
    if (t == 0 && ticket_s == (int)gridDim.x - 1) {
        double total = atomicAdd(loss_acc, 0.0);
        *loss_out = (float)(1.25 * total * (1.0 / (double)((long)N_VEC * DIM)));
    }
}

extern "C" void kernel_launch(void* const* d_in, const int* in_sizes, int n_in,
                              void* d_out, int out_size, void* d_ws, size_t ws_size,
                              hipStream_t stream) {
    const float* z  = (const float*)d_in[0];
    const float* cb = (const float*)d_in[1];
    float* out      = (float*)d_out;
    char*  ws       = (char*)d_ws;

    double* loss_acc = (double*)ws;
    int*    counter  = (int*)(ws + 8);
    int*    done     = (int*)(ws + 12);
    float*  norms    = (float*)(ws + 64);
    short*  ehg      = (short*)(ws + 8192);
    short*  elg      = (short*)(ws + 139264);
    int*    worklist = (int*)(ws + 270336);

    int cap = WLCAP;
    long avail = ((long)ws_size - 270336) / 4;
    if (avail < cap) cap = (avail > 0) ? (int)avail : 0;

    vq_prep<<<dim3(KCODE / 16), dim3(256), 0, stream>>>(
        cb, norms, ehg, elg, loss_acc, counter, done);
    vq_main<<<dim3(N_VEC / BLK_ROWS), dim3(256), 0, stream>>>(
        z, cb, norms, ehg, elg, out, loss_acc, counter, worklist, cap);
    vq_rescue<<<dim3(512), dim3(256), 0, stream>>>(
        z, cb, out, loss_acc, counter, worklist, cap, done, out + (out_size - 1));
}

// Round 11
// 294.530 us; speedup vs baseline: 7.9486x; 2.0339x over previous
//
#include <hip/hip_runtime.h>

#define N_VEC 131072   // B*H*W
#define DIM   64
#define KCODE 1024
#define HW    4096
#define DHW   262144
#define EPS   0.125f   // near-tie margin (validated r4-r8)
#define WLCAP 8192     // count ~3700 observed; 2.2x headroom
#define BLK_ROWS 128   // rows per block; 4 waves x 32 rows
#define PITCH 72       // shorts per LDS row (144 B)
#define BCHUNK 64      // main: codes per LDS-staged codebook chunk
#define NBCHUNK 16

typedef short short8 __attribute__((ext_vector_type(8)));
typedef float f32x4  __attribute__((ext_vector_type(4)));

// ws layout (bytes) -- proven 401408 footprint:
//   0      : double loss accumulator
//   8      : int flagged counter
//   12     : int done-ticket counter
//   64     : norms f32[1024]
//   8192   : eh  bf16-bits short[65536]
//   139264 : el  bf16-bits short[65536]
//   270336 : worklist int[WLCAP]          (ends 303104)

__device__ __forceinline__ unsigned short f32_to_bf16_rne(float x) {
    unsigned u = __float_as_uint(x);
    u += 0x7FFFu + ((u >> 16) & 1u);
    return (unsigned short)(u >> 16);
}
__device__ __forceinline__ float bf16_to_f32(unsigned short h) {
    return __uint_as_float((unsigned)h << 16);
}

__global__ __launch_bounds__(256) void vq_prep(
    const float* __restrict__ cb, float* __restrict__ norms,
    short* __restrict__ ehg, short* __restrict__ elg,
    double* __restrict__ loss_acc, int* __restrict__ counter,
    int* __restrict__ done)
{
    const int t = threadIdx.x;
    if (blockIdx.x == 0 && t == 0) { *loss_acc = 0.0; *counter = 0; *done = 0; }

    const int k    = blockIdx.x * 16 + (t >> 4);
    const int part = t & 15;
    const float4 v = *(const float4*)(cb + k * DIM + part * 4);

    float s = 0.f;
    s = fmaf(v.x, v.x, s); s = fmaf(v.y, v.y, s);
    s = fmaf(v.z, v.z, s); s = fmaf(v.w, v.w, s);
    #pragma unroll
    for (int m = 1; m <= 8; m <<= 1) s += __shfl_xor(s, m, 64);
    if (part == 0) norms[k] = s;

    short h[4], l[4];
    const float vv[4] = { v.x, v.y, v.z, v.w };
    #pragma unroll
    for (int j = 0; j < 4; ++j) {
        unsigned short hh = f32_to_bf16_rne(vv[j]);
        unsigned short ll = f32_to_bf16_rne(vv[j] - bf16_to_f32(hh));
        h[j] = (short)hh; l[j] = (short)ll;
    }
    *(short4*)(ehg + k * DIM + part * 4) = make_short4(h[0], h[1], h[2], h[3]);
    *(short4*)(elg + k * DIM + part * 4) = make_short4(l[0], l[1], l[2], l[3]);
}

// Main v6 (unchanged from R5/R6): LDS-staged B double-buffered, per-block LDS
// aggregation of worklist slots -> ONE global atomicAdd per block.
__global__ __launch_bounds__(256, 2) void vq_main(
    const float* __restrict__ z, const float* __restrict__ cb,
    const float* __restrict__ norms, const short* __restrict__ ehg,
    const short* __restrict__ elg, float* __restrict__ out,
    double* __restrict__ loss_acc, int* __restrict__ counter,
    int* __restrict__ worklist, int cap)
{
    __shared__ short  zh[BLK_ROWS * PITCH];   // hi(-2z) bf16 bits, [row=hw][d]
    __shared__ short  zl[BLK_ROWS * PITCH];
    __shared__ short  ebh0[BCHUNK * PITCH];   // codebook chunk hi, double-buffered
    __shared__ short  ebh1[BCHUNK * PITCH];
    __shared__ short  ebl0[BCHUNK * PITCH];
    __shared__ short  ebl1[BCHUNK * PITCH];
    __shared__ float  nsh[KCODE];             // norms, block-resident
    __shared__ int    kidx[BLK_ROWS];
    __shared__ float  wsum[4];
    __shared__ int    blkrows[BLK_ROWS];      // flagged row-local ids
    __shared__ int    blkcnt;
    __shared__ int    blkbase;

    const int t   = threadIdx.x;              // 0..255
    const int n0  = blockIdx.x * BLK_ROWS;
    const int b   = n0 >> 12;
    const int hw0 = n0 & 4095;

    const int lane = t & 63;
    const int wave = t >> 6;                  // 0..3
    const int l15  = lane & 15;
    const int quad = lane >> 4;
    const int rowbase = wave * 32;            // 2 row-tiles per wave

    if (t == 0) blkcnt = 0;

    // ---- stage z -> LDS (8 float4/thread, register transpose, b128 writes) ----
    {
        const int hwl   = (t & 31) * 4;       // 4 consecutive rows
        const int dbase = (t >> 5) * 8;       // 8 consecutive d
        float4 v[8];
        #pragma unroll
        for (int p = 0; p < 8; ++p)
            v[p] = *(const float4*)(z + (size_t)b * DHW + (size_t)(dbase + p) * HW + hw0 + hwl);
        #pragma unroll
        for (int c = 0; c < 4; ++c) {
            short8 hi, lo;
            #pragma unroll
            for (int p = 0; p < 8; ++p) {
                const float* vp = (const float*)&v[p];
                float f = -2.0f * vp[c];
                unsigned short hh = f32_to_bf16_rne(f);
                unsigned short ll = f32_to_bf16_rne(f - bf16_to_f32(hh));
                hi[p] = (short)hh; lo[p] = (short)ll;
            }
            *(short8*)&zh[(hwl + c) * PITCH + dbase] = hi;
            *(short8*)&zl[(hwl + c) * PITCH + dbase] = lo;
        }
    }

    // ---- stage norms -> LDS ----
    #pragma unroll
    for (int j = 0; j < 4; ++j) nsh[t + j * 256] = norms[t + j * 256];

    // ---- B-staging prologue: thread owns 32 B hi + 32 B lo per chunk ----
    const int cc = t >> 2;                    // code within chunk (0..63)
    const int pp = (t & 3) * 16;              // short offset within code row
    short8 pf0[4], pf1[4];                    // [0..1]=hi, [2..3]=lo
    #pragma unroll
    for (int j = 0; j < 2; ++j) {
        pf0[j]     = *(const short8*)(ehg + (size_t)cc * DIM + pp + j * 8);
        pf0[2 + j] = *(const short8*)(elg + (size_t)cc * DIM + pp + j * 8);
        pf1[j]     = *(const short8*)(ehg + (size_t)(BCHUNK + cc) * DIM + pp + j * 8);
        pf1[2 + j] = *(const short8*)(elg + (size_t)(BCHUNK + cc) * DIM + pp + j * 8);
    }
    __syncthreads();                          // z + norms ready (prologue loads drain once)

    // ---- A-fragments (32 VGPRs, resident) ----
    short8 a_h[2][2], a_l[2][2];
    #pragma unroll
    for (int rt = 0; rt < 2; ++rt)
        #pragma unroll
        for (int kt = 0; kt < 2; ++kt) {
            const int idx = (rowbase + rt * 16 + l15) * PITCH + kt * 32 + quad * 8;
            a_h[rt][kt] = *(const short8*)&zh[idx];
            a_l[rt][kt] = *(const short8*)&zl[idx];
        }

    // ---- write chunk 0 into buf0 ----
    #pragma unroll
    for (int j = 0; j < 2; ++j) {
        *(short8*)&ebh0[cc * PITCH + pp + j * 8] = pf0[j];
        *(short8*)&ebl0[cc * PITCH + pp + j * 8] = pf0[2 + j];
    }
    __syncthreads();                          // buf0 ready

    float best[2][4], best2[2][4];
    #pragma unroll
    for (int rt = 0; rt < 2; ++rt)
        #pragma unroll
        for (int r = 0; r < 4; ++r) { best[rt][r] = 3.0e38f; best2[rt][r] = 3.0e38f; }

    // chunk body: issue ch+2 loads -> pfL; compute chunk ch from (bhR,blR);
    // write pfW (chunk ch+1) -> (bhW,blW); barrier.
    auto body = [&](int ch, const short* bhR, const short* blR,
                    short* bhW, short* blW, short8 (&pfL)[4], short8 (&pfW)[4]) {
        if (ch + 2 < NBCHUNK) {
            const size_t gb = (size_t)((ch + 2) * BCHUNK + cc) * DIM + pp;
            #pragma unroll
            for (int j = 0; j < 2; ++j) {
                pfL[j]     = *(const short8*)(ehg + gb + j * 8);
                pfL[2 + j] = *(const short8*)(elg + gb + j * 8);
            }
        }
        // hoist the 4 norm reads (they gate each MFMA chain's acc init)
        float nrm4[4];
        #pragma unroll
        for (int ct = 0; ct < 4; ++ct) nrm4[ct] = nsh[ch * BCHUNK + ct * 16 + l15];

        #pragma unroll
        for (int ct = 0; ct < 4; ++ct) {
            const int crow = ct * 16 + l15;
            short8 Bh0 = *(const short8*)&bhR[crow * PITCH + quad * 8];
            short8 Bh1 = *(const short8*)&bhR[crow * PITCH + 32 + quad * 8];
            short8 Bl0 = *(const short8*)&blR[crow * PITCH + quad * 8];
            short8 Bl1 = *(const short8*)&blR[crow * PITCH + 32 + quad * 8];
            const unsigned colbits = (unsigned)(ch * BCHUNK + crow);
            const float nrm = nrm4[ct];
            #pragma unroll
            for (int rt = 0; rt < 2; ++rt) {
                f32x4 acc = { nrm, nrm, nrm, nrm };
                acc = __builtin_amdgcn_mfma_f32_16x16x32_bf16(a_h[rt][0], Bh0, acc, 0, 0, 0);
                acc = __builtin_amdgcn_mfma_f32_16x16x32_bf16(a_h[rt][1], Bh1, acc, 0, 0, 0);
                acc = __builtin_amdgcn_mfma_f32_16x16x32_bf16(a_h[rt][0], Bl0, acc, 0, 0, 0);
                acc = __builtin_amdgcn_mfma_f32_16x16x32_bf16(a_h[rt][1], Bl1, acc, 0, 0, 0);
                acc = __builtin_amdgcn_mfma_f32_16x16x32_bf16(a_l[rt][0], Bh0, acc, 0, 0, 0);
                acc = __builtin_amdgcn_mfma_f32_16x16x32_bf16(a_l[rt][1], Bh1, acc, 0, 0, 0);
                #pragma unroll
                for (int r = 0; r < 4; ++r) {
                    float p = __uint_as_float((__float_as_uint(acc[r]) & 0xFFFFFC00u) | colbits);
                    best2[rt][r] = fminf(best2[rt][r], fmaxf(best[rt][r], p));
                    best[rt][r]  = fminf(best[rt][r], p);
                }
            }
        }
        if (ch + 1 < NBCHUNK) {
            #pragma unroll
            for (int j = 0; j < 2; ++j) {
                *(short8*)&bhW[cc * PITCH + pp + j * 8] = pfW[j];
                *(short8*)&blW[cc * PITCH + pp + j * 8] = pfW[2 + j];
            }
        }
        __syncthreads();
    };

    for (int chp = 0; chp < 8; ++chp) {
        body(2 * chp,     ebh0, ebl0, ebh1, ebl1, pf0, pf1);
        body(2 * chp + 1, ebh1, ebl1, ebh0, ebl0, pf1, pf0);
    }

    // ---- merge across 16 code-lanes; each wave has complete top-2 for its rows ----
    #pragma unroll
    for (int rt = 0; rt < 2; ++rt)
        #pragma unroll
        for (int r = 0; r < 4; ++r) {
            float bb = best[rt][r], b2 = best2[rt][r];
            #pragma unroll
            for (int m = 1; m <= 8; m <<= 1) {
                float ob  = __shfl_xor(bb, m, 64);
                float ob2 = __shfl_xor(b2, m, 64);
                b2 = fminf(fminf(b2, ob2), fmaxf(bb, ob));
                bb = fminf(bb, ob);
            }
            best[rt][r] = bb; best2[rt][r] = b2;
        }

    // ---- per-row result: flags into LDS list (LDS atomics only) ----
    if (l15 == 0) {
        #pragma unroll
        for (int rt = 0; rt < 2; ++rt)
            #pragma unroll
            for (int r = 0; r < 4; ++r) {
                unsigned ub = __float_as_uint(best[rt][r]);
                int k = (int)(ub & 1023u);
                float sb  = __uint_as_float(ub & 0xFFFFFC00u);
                float sb2 = __uint_as_float(__float_as_uint(best2[rt][r]) & 0xFFFFFC00u);
                int rowl = rowbase + rt * 16 + quad * 4 + r;
                int flag = 0;
                if (sb2 - sb < EPS) {
                    int p = atomicAdd(&blkcnt, 1);   // LDS atomic, per-CU fast
                    blkrows[p] = rowl; flag = 1;
                }
                kidx[rowl] = k | (flag << 15);
            }
    }
    __syncthreads();
    // ---- ONE global atomic per block reserves the slot range ----
    if (t == 0) blkbase = (blkcnt > 0) ? atomicAdd(counter, blkcnt) : 0;
    __syncthreads();
    if (t < blkcnt) {
        const int rowl = blkrows[t];
        const int slot = blkbase + t;
        if (slot < cap) worklist[slot] = n0 + rowl;
        else            kidx[rowl] &= 0x7FFF;   // overflow: un-flag, epilogue handles
    }
    __syncthreads();

    // ---- epilogue: row = t&127, dgrp = t>>7 covers 32 d; coalesced stores ----
    float lsum = 0.f;
    {
        const int row  = t & 127;
        const int d0   = (t >> 7) * 32;
        const int ki   = kidx[row];
        const int k    = ki & 1023;
        const int flag = (ki >> 15) & 1;
        if (!flag) {
            const float4* cbr = (const float4*)(cb + k * DIM + d0);
            const short8* zhr = (const short8*)&zh[row * PITCH + d0];
            const short8* zlr = (const short8*)&zl[row * PITCH + d0];
            float* op = out + (size_t)b * DHW + (size_t)d0 * HW + hw0 + row;
            #pragma unroll
            for (int g = 0; g < 4; ++g) {
                short8 hh = zhr[g];
                short8 ll = zlr[g];
                float4 e0 = cbr[2 * g];
                float4 e1 = cbr[2 * g + 1];
                const float ev[8] = { e0.x, e0.y, e0.z, e0.w, e1.x, e1.y, e1.z, e1.w };
                #pragma unroll
                for (int j = 0; j < 8; ++j) {
                    float zv = -0.5f * (bf16_to_f32((unsigned short)hh[j]) +
                                        bf16_to_f32((unsigned short)ll[j]));
                    op[(size_t)(g * 8 + j) * HW] = ev[j];
                    float df = ev[j] - zv;
                    lsum = fmaf(df, df, lsum);
                }
            }
        }
    }
    #pragma unroll
    for (int off = 32; off > 0; off >>= 1) lsum += __shfl_down(lsum, off, 64);
    if (lane == 0) wsum[wave] = lsum;
    __syncthreads();
    if (t == 0)
        atomicAdd(loss_acc, (double)((wsum[0] + wsum[1]) + (wsum[2] + wsum[3])));
}

// Rescue v8 = v7 decomposition (one vector/block-iteration, wave w scans chunk
// w, cb read directly from the INPUT buffer) with codegen disciplined:
// - #pragma unroll 1 on the row loop: rows truly sequential, ~25 live VGPRs.
// - #pragma unroll 4 on the q loop: 4 float4 in flight, no full hoist.
//   (R10's `#pragma unroll` everywhere fully unrolled 64 float4 loads ->
//   VGPR=256 cap -> scratch spill -> 321MB FETCH / 96MB WRITE / 461 us.)
// - nj/dt each split into 2 accumulators (x,y | z,w): halves the f64 dep
//   chain. Last-ulp reordering only (~2^-50), invisible at f32 tolerance.
// Packed-u64 order-preserving min reproduces min-k tie-break. Loss: ONE f64
// atomic per block; ticket finalizes.
__global__ __launch_bounds__(256) void vq_rescue(
    const float* __restrict__ z, const float* __restrict__ cb,
    float* __restrict__ out, double* __restrict__ loss_acc,
    const int* __restrict__ counter, const int* __restrict__ worklist, int cap,
    int* __restrict__ done, float* __restrict__ loss_out)
{
    __shared__ float zsh[DIM];                 // one z row
    __shared__ unsigned long long pls[4];      // per-wave packed partials

    int count = *counter; if (count > cap) count = cap;
    const int t    = threadIdx.x;
    const int wave = t >> 6;
    const int lane = t & 63;

    double lloss = 0.0;                        // wave0/lane0 accumulator

    for (int i = blockIdx.x; i < count; i += gridDim.x) {
        const int n  = worklist[i];
        const int bb = n >> 12, hw = n & 4095;
        if (wave == 0)
            zsh[lane] = z[(size_t)bb * DHW + (size_t)lane * HW + hw];
        __syncthreads();                       // z row visible

        // per-wave ||z||^2 (uniform value, recomputed cheaply per wave)
        const float zl = zsh[lane];
        double zn = (double)zl * (double)zl;
        #pragma unroll
        for (int m = 1; m <= 32; m <<= 1) zn += __shfl_xor(zn, m, 64);

        unsigned long long best = ~0ull;
        #pragma unroll 1
        for (int r = 0; r < 4; ++r) {
            const int k = wave * 256 + r * 64 + lane;
            const float4* cr = (const float4*)(cb + (size_t)k * DIM);
            double nj0 = 0.0, nj1 = 0.0, dt0 = 0.0, dt1 = 0.0;
            #pragma unroll 4
            for (int q = 0; q < 16; ++q) {
                const float4 c  = cr[q];
                const float4 zv = *(const float4*)&zsh[q * 4];
                nj0 = fma((double)c.x, (double)c.x, nj0);
                nj1 = fma((double)c.y, (double)c.y, nj1);
                nj0 = fma((double)c.z, (double)c.z, nj0);
                nj1 = fma((double)c.w, (double)c.w, nj1);
                dt0 = fma((double)c.x, (double)zv.x, dt0);
                dt1 = fma((double)c.y, (double)zv.y, dt1);
                dt0 = fma((double)c.z, (double)zv.z, dt0);
                dt1 = fma((double)c.w, (double)zv.w, dt1);
            }
            const double nj = nj0 + nj1;
            const double dt = dt0 + dt1;
            const double p = fmax(fma(-2.0, dt, nj) + zn, 0.0);
            const unsigned long long q64 =
                ((unsigned long long)__double_as_longlong(p) & ~1023ull)
                | (unsigned long long)k;
            if (q64 < best) best = q64;
        }

        #pragma unroll
        for (int m = 1; m <= 32; m <<= 1) {
            unsigned long long o = __shfl_xor(best, m, 64);
            if (o < best) best = o;
        }
        if (lane == 0) pls[wave] = best;
        __syncthreads();                       // partials visible

        if (wave == 0) {
            unsigned long long p0 = pls[0], p1 = pls[1];
            unsigned long long p2 = pls[2], p3 = pls[3];
            unsigned long long p = p0 < p1 ? p0 : p1;
            if (p2 < p) p = p2;
            if (p3 < p) p = p3;
            const int bk = (int)(p & 1023ull);
            out[(size_t)bb * DHW + (size_t)lane * HW + hw] = cb[(size_t)bk * DIM + lane];
            if (lane == 0)
                lloss += __longlong_as_double((long long)(p & ~1023ull));
        }
    }

    if (wave == 0 && lane == 0 && lloss != 0.0) atomicAdd(loss_acc, lloss);

    __threadfence();
    __shared__ int ticket_s;
    if (t == 0) ticket_s = atomicAdd(done, 1);
    __syncthreads();
    if (t == 0 && ticket_s == (int)gridDim.x - 1) {
        double total = atomicAdd(loss_acc, 0.0);
        *loss_out = (float)(1.25 * total * (1.0 / (double)((long)N_VEC * DIM)));
    }
}

extern "C" void kernel_launch(void* const* d_in, const int* in_sizes, int n_in,
                              void* d_out, int out_size, void* d_ws, size_t ws_size,
                              hipStream_t stream) {
    const float* z  = (const float*)d_in[0];
    const float* cb = (const float*)d_in[1];
    float* out      = (float*)d_out;
    char*  ws       = (char*)d_ws;

    double* loss_acc = (double*)ws;
    int*    counter  = (int*)(ws + 8);
    int*    done     = (int*)(ws + 12);
    float*  norms    = (float*)(ws + 64);
    short*  ehg      = (short*)(ws + 8192);
    short*  elg      = (short*)(ws + 139264);
    int*    worklist = (int*)(ws + 270336);

    int cap = WLCAP;
    long avail = ((long)ws_size - 270336) / 4;
    if (avail < cap) cap = (avail > 0) ? (int)avail : 0;

    vq_prep<<<dim3(KCODE / 16), dim3(256), 0, stream>>>(
        cb, norms, ehg, elg, loss_acc, counter, done);
    vq_main<<<dim3(N_VEC / BLK_ROWS), dim3(256), 0, stream>>>(
        z, cb, norms, ehg, elg, out, loss_acc, counter, worklist, cap);
    vq_rescue<<<dim3(512), dim3(256), 0, stream>>>(
        z, cb, out, loss_acc, counter, worklist, cap, done, out + (out_size - 1));
}

// Round 12
// 256.069 us; speedup vs baseline: 9.1424x; 1.1502x over previous
//
#include <hip/hip_runtime.h>

#define N_VEC 131072   // B*H*W
#define DIM   64
#define KCODE 1024
#define HW    4096
#define DHW   262144
#define EPS   0.125f   // near-tie margin (validated r4-r8)
#define WLCAP 8192     // count ~3700 observed; 2.2x headroom
#define BLK_ROWS 128   // rows per block; 4 waves x 32 rows
#define PITCH 72       // shorts per LDS row (144 B)
#define BCHUNK 64      // main: codes per LDS-staged codebook chunk
#define NBCHUNK 16
#define RGRID 2048     // rescue grid; <=2 iterations/block at count~3700

typedef short short8 __attribute__((ext_vector_type(8)));
typedef float f32x4  __attribute__((ext_vector_type(4)));

// ws layout (bytes) -- proven 401408 footprint:
//   0      : double loss accumulator
//   8      : int flagged counter
//   12     : int done-ticket counter (unused now)
//   64     : norms f32[1024]
//   8192   : eh  bf16-bits short[65536]
//   139264 : el  bf16-bits short[65536]
//   270336 : worklist int[WLCAP]          (ends 303104)
//   303104 : lsum f64[RGRID]              (16 KB, ends 319488)

__device__ __forceinline__ unsigned short f32_to_bf16_rne(float x) {
    unsigned u = __float_as_uint(x);
    u += 0x7FFFu + ((u >> 16) & 1u);
    return (unsigned short)(u >> 16);
}
__device__ __forceinline__ float bf16_to_f32(unsigned short h) {
    return __uint_as_float((unsigned)h << 16);
}

__global__ __launch_bounds__(256) void vq_prep(
    const float* __restrict__ cb, float* __restrict__ norms,
    short* __restrict__ ehg, short* __restrict__ elg,
    double* __restrict__ loss_acc, int* __restrict__ counter,
    int* __restrict__ done)
{
    const int t = threadIdx.x;
    if (blockIdx.x == 0 && t == 0) { *loss_acc = 0.0; *counter = 0; *done = 0; }

    const int k    = blockIdx.x * 16 + (t >> 4);
    const int part = t & 15;
    const float4 v = *(const float4*)(cb + k * DIM + part * 4);

    float s = 0.f;
    s = fmaf(v.x, v.x, s); s = fmaf(v.y, v.y, s);
    s = fmaf(v.z, v.z, s); s = fmaf(v.w, v.w, s);
    #pragma unroll
    for (int m = 1; m <= 8; m <<= 1) s += __shfl_xor(s, m, 64);
    if (part == 0) norms[k] = s;

    short h[4], l[4];
    const float vv[4] = { v.x, v.y, v.z, v.w };
    #pragma unroll
    for (int j = 0; j < 4; ++j) {
        unsigned short hh = f32_to_bf16_rne(vv[j]);
        unsigned short ll = f32_to_bf16_rne(vv[j] - bf16_to_f32(hh));
        h[j] = (short)hh; l[j] = (short)ll;
    }
    *(short4*)(ehg + k * DIM + part * 4) = make_short4(h[0], h[1], h[2], h[3]);
    *(short4*)(elg + k * DIM + part * 4) = make_short4(l[0], l[1], l[2], l[3]);
}

// Main v6 (unchanged from R5/R6): LDS-staged B double-buffered, per-block LDS
// aggregation of worklist slots -> ONE global atomicAdd per block.
__global__ __launch_bounds__(256, 2) void vq_main(
    const float* __restrict__ z, const float* __restrict__ cb,
    const float* __restrict__ norms, const short* __restrict__ ehg,
    const short* __restrict__ elg, float* __restrict__ out,
    double* __restrict__ loss_acc, int* __restrict__ counter,
    int* __restrict__ worklist, int cap)
{
    __shared__ short  zh[BLK_ROWS * PITCH];   // hi(-2z) bf16 bits, [row=hw][d]
    __shared__ short  zl[BLK_ROWS * PITCH];
    __shared__ short  ebh0[BCHUNK * PITCH];   // codebook chunk hi, double-buffered
    __shared__ short  ebh1[BCHUNK * PITCH];
    __shared__ short  ebl0[BCHUNK * PITCH];
    __shared__ short  ebl1[BCHUNK * PITCH];
    __shared__ float  nsh[KCODE];             // norms, block-resident
    __shared__ int    kidx[BLK_ROWS];
    __shared__ float  wsum[4];
    __shared__ int    blkrows[BLK_ROWS];      // flagged row-local ids
    __shared__ int    blkcnt;
    __shared__ int    blkbase;

    const int t   = threadIdx.x;              // 0..255
    const int n0  = blockIdx.x * BLK_ROWS;
    const int b   = n0 >> 12;
    const int hw0 = n0 & 4095;

    const int lane = t & 63;
    const int wave = t >> 6;                  // 0..3
    const int l15  = lane & 15;
    const int quad = lane >> 4;
    const int rowbase = wave * 32;            // 2 row-tiles per wave

    if (t == 0) blkcnt = 0;

    // ---- stage z -> LDS (8 float4/thread, register transpose, b128 writes) ----
    {
        const int hwl   = (t & 31) * 4;       // 4 consecutive rows
        const int dbase = (t >> 5) * 8;       // 8 consecutive d
        float4 v[8];
        #pragma unroll
        for (int p = 0; p < 8; ++p)
            v[p] = *(const float4*)(z + (size_t)b * DHW + (size_t)(dbase + p) * HW + hw0 + hwl);
        #pragma unroll
        for (int c = 0; c < 4; ++c) {
            short8 hi, lo;
            #pragma unroll
            for (int p = 0; p < 8; ++p) {
                const float* vp = (const float*)&v[p];
                float f = -2.0f * vp[c];
                unsigned short hh = f32_to_bf16_rne(f);
                unsigned short ll = f32_to_bf16_rne(f - bf16_to_f32(hh));
                hi[p] = (short)hh; lo[p] = (short)ll;
            }
            *(short8*)&zh[(hwl + c) * PITCH + dbase] = hi;
            *(short8*)&zl[(hwl + c) * PITCH + dbase] = lo;
        }
    }

    // ---- stage norms -> LDS ----
    #pragma unroll
    for (int j = 0; j < 4; ++j) nsh[t + j * 256] = norms[t + j * 256];

    // ---- B-staging prologue: thread owns 32 B hi + 32 B lo per chunk ----
    const int cc = t >> 2;                    // code within chunk (0..63)
    const int pp = (t & 3) * 16;              // short offset within code row
    short8 pf0[4], pf1[4];                    // [0..1]=hi, [2..3]=lo
    #pragma unroll
    for (int j = 0; j < 2; ++j) {
        pf0[j]     = *(const short8*)(ehg + (size_t)cc * DIM + pp + j * 8);
        pf0[2 + j] = *(const short8*)(elg + (size_t)cc * DIM + pp + j * 8);
        pf1[j]     = *(const short8*)(ehg + (size_t)(BCHUNK + cc) * DIM + pp + j * 8);
        pf1[2 + j] = *(const short8*)(elg + (size_t)(BCHUNK + cc) * DIM + pp + j * 8);
    }
    __syncthreads();                          // z + norms ready (prologue loads drain once)

    // ---- A-fragments (32 VGPRs, resident) ----
    short8 a_h[2][2], a_l[2][2];
    #pragma unroll
    for (int rt = 0; rt < 2; ++rt)
        #pragma unroll
        for (int kt = 0; kt < 2; ++kt) {
            const int idx = (rowbase + rt * 16 + l15) * PITCH + kt * 32 + quad * 8;
            a_h[rt][kt] = *(const short8*)&zh[idx];
            a_l[rt][kt] = *(const short8*)&zl[idx];
        }

    // ---- write chunk 0 into buf0 ----
    #pragma unroll
    for (int j = 0; j < 2; ++j) {
        *(short8*)&ebh0[cc * PITCH + pp + j * 8] = pf0[j];
        *(short8*)&ebl0[cc * PITCH + pp + j * 8] = pf0[2 + j];
    }
    __syncthreads();                          // buf0 ready

    float best[2][4], best2[2][4];
    #pragma unroll
    for (int rt = 0; rt < 2; ++rt)
        #pragma unroll
        for (int r = 0; r < 4; ++r) { best[rt][r] = 3.0e38f; best2[rt][r] = 3.0e38f; }

    // chunk body: issue ch+2 loads -> pfL; compute chunk ch from (bhR,blR);
    // write pfW (chunk ch+1) -> (bhW,blW); barrier.
    auto body = [&](int ch, const short* bhR, const short* blR,
                    short* bhW, short* blW, short8 (&pfL)[4], short8 (&pfW)[4]) {
        if (ch + 2 < NBCHUNK) {
            const size_t gb = (size_t)((ch + 2) * BCHUNK + cc) * DIM + pp;
            #pragma unroll
            for (int j = 0; j < 2; ++j) {
                pfL[j]     = *(const short8*)(ehg + gb + j * 8);
                pfL[2 + j] = *(const short8*)(elg + gb + j * 8);
            }
        }
        // hoist the 4 norm reads (they gate each MFMA chain's acc init)
        float nrm4[4];
        #pragma unroll
        for (int ct = 0; ct < 4; ++ct) nrm4[ct] = nsh[ch * BCHUNK + ct * 16 + l15];

        #pragma unroll
        for (int ct = 0; ct < 4; ++ct) {
            const int crow = ct * 16 + l15;
            short8 Bh0 = *(const short8*)&bhR[crow * PITCH + quad * 8];
            short8 Bh1 = *(const short8*)&bhR[crow * PITCH + 32 + quad * 8];
            short8 Bl0 = *(const short8*)&blR[crow * PITCH + quad * 8];
            short8 Bl1 = *(const short8*)&blR[crow * PITCH + 32 + quad * 8];
            const unsigned colbits = (unsigned)(ch * BCHUNK + crow);
            const float nrm = nrm4[ct];
            #pragma unroll
            for (int rt = 0; rt < 2; ++rt) {
                f32x4 acc = { nrm, nrm, nrm, nrm };
                acc = __builtin_amdgcn_mfma_f32_16x16x32_bf16(a_h[rt][0], Bh0, acc, 0, 0, 0);
                acc = __builtin_amdgcn_mfma_f32_16x16x32_bf16(a_h[rt][1], Bh1, acc, 0, 0, 0);
                acc = __builtin_amdgcn_mfma_f32_16x16x32_bf16(a_h[rt][0], Bl0, acc, 0, 0, 0);
                acc = __builtin_amdgcn_mfma_f32_16x16x32_bf16(a_h[rt][1], Bl1, acc, 0, 0, 0);
                acc = __builtin_amdgcn_mfma_f32_16x16x32_bf16(a_l[rt][0], Bh0, acc, 0, 0, 0);
                acc = __builtin_amdgcn_mfma_f32_16x16x32_bf16(a_l[rt][1], Bh1, acc, 0, 0, 0);
                #pragma unroll
                for (int r = 0; r < 4; ++r) {
                    float p = __uint_as_float((__float_as_uint(acc[r]) & 0xFFFFFC00u) | colbits);
                    best2[rt][r] = fminf(best2[rt][r], fmaxf(best[rt][r], p));
                    best[rt][r]  = fminf(best[rt][r], p);
                }
            }
        }
        if (ch + 1 < NBCHUNK) {
            #pragma unroll
            for (int j = 0; j < 2; ++j) {
                *(short8*)&bhW[cc * PITCH + pp + j * 8] = pfW[j];
                *(short8*)&blW[cc * PITCH + pp + j * 8] = pfW[2 + j];
            }
        }
        __syncthreads();
    };

    for (int chp = 0; chp < 8; ++chp) {
        body(2 * chp,     ebh0, ebl0, ebh1, ebl1, pf0, pf1);
        body(2 * chp + 1, ebh1, ebl1, ebh0, ebl0, pf1, pf0);
    }

    // ---- merge across 16 code-lanes; each wave has complete top-2 for its rows ----
    #pragma unroll
    for (int rt = 0; rt < 2; ++rt)
        #pragma unroll
        for (int r = 0; r < 4; ++r) {
            float bb = best[rt][r], b2 = best2[rt][r];
            #pragma unroll
            for (int m = 1; m <= 8; m <<= 1) {
                float ob  = __shfl_xor(bb, m, 64);
                float ob2 = __shfl_xor(b2, m, 64);
                b2 = fminf(fminf(b2, ob2), fmaxf(bb, ob));
                bb = fminf(bb, ob);
            }
            best[rt][r] = bb; best2[rt][r] = b2;
        }

    // ---- per-row result: flags into LDS list (LDS atomics only) ----
    if (l15 == 0) {
        #pragma unroll
        for (int rt = 0; rt < 2; ++rt)
            #pragma unroll
            for (int r = 0; r < 4; ++r) {
                unsigned ub = __float_as_uint(best[rt][r]);
                int k = (int)(ub & 1023u);
                float sb  = __uint_as_float(ub & 0xFFFFFC00u);
                float sb2 = __uint_as_float(__float_as_uint(best2[rt][r]) & 0xFFFFFC00u);
                int rowl = rowbase + rt * 16 + quad * 4 + r;
                int flag = 0;
                if (sb2 - sb < EPS) {
                    int p = atomicAdd(&blkcnt, 1);   // LDS atomic, per-CU fast
                    blkrows[p] = rowl; flag = 1;
                }
                kidx[rowl] = k | (flag << 15);
            }
    }
    __syncthreads();
    // ---- ONE global atomic per block reserves the slot range ----
    if (t == 0) blkbase = (blkcnt > 0) ? atomicAdd(counter, blkcnt) : 0;
    __syncthreads();
    if (t < blkcnt) {
        const int rowl = blkrows[t];
        const int slot = blkbase + t;
        if (slot < cap) worklist[slot] = n0 + rowl;
        else            kidx[rowl] &= 0x7FFF;   // overflow: un-flag, epilogue handles
    }
    __syncthreads();

    // ---- epilogue: row = t&127, dgrp = t>>7 covers 32 d; coalesced stores ----
    float lsum = 0.f;
    {
        const int row  = t & 127;
        const int d0   = (t >> 7) * 32;
        const int ki   = kidx[row];
        const int k    = ki & 1023;
        const int flag = (ki >> 15) & 1;
        if (!flag) {
            const float4* cbr = (const float4*)(cb + k * DIM + d0);
            const short8* zhr = (const short8*)&zh[row * PITCH + d0];
            const short8* zlr = (const short8*)&zl[row * PITCH + d0];
            float* op = out + (size_t)b * DHW + (size_t)d0 * HW + hw0 + row;
            #pragma unroll
            for (int g = 0; g < 4; ++g) {
                short8 hh = zhr[g];
                short8 ll = zlr[g];
                float4 e0 = cbr[2 * g];
                float4 e1 = cbr[2 * g + 1];
                const float ev[8] = { e0.x, e0.y, e0.z, e0.w, e1.x, e1.y, e1.z, e1.w };
                #pragma unroll
                for (int j = 0; j < 8; ++j) {
                    float zv = -0.5f * (bf16_to_f32((unsigned short)hh[j]) +
                                        bf16_to_f32((unsigned short)ll[j]));
                    op[(size_t)(g * 8 + j) * HW] = ev[j];
                    float df = ev[j] - zv;
                    lsum = fmaf(df, df, lsum);
                }
            }
        }
    }
    #pragma unroll
    for (int off = 32; off > 0; off >>= 1) lsum += __shfl_down(lsum, off, 64);
    if (lane == 0) wsum[wave] = lsum;
    __syncthreads();
    if (t == 0)
        atomicAdd(loss_acc, (double)((wsum[0] + wsum[1]) + (wsum[2] + wsum[3])));
}

// Rescue v9 = v8 inner loop (proven VGPR=52, no spill) with the two remaining
// structural fixes:
// - grid 512 -> 2048: <=2 iterations/block, up to 32 waves/CU schedulable
//   (R11 was grid-starved: 8 waves/CU, 7.2 serial vectors/block = 162 us of
//   exposed latency over a ~25-50 us f64 VALU floor).
// - ZERO same-address RMWs: no done-ticket, no loss atomic. Each block writes
//   its f64 loss partial to a distinct ws slot; stream-ordered vq_finalize
//   reduces them. (512-2048 ticket+loss atomics were a 15-60 us convoy tail.)
__global__ __launch_bounds__(256) void vq_rescue(
    const float* __restrict__ z, const float* __restrict__ cb,
    float* __restrict__ out,
    const int* __restrict__ counter, const int* __restrict__ worklist, int cap,
    double* __restrict__ lsum_ws)
{
    __shared__ float zsh[DIM];                 // one z row
    __shared__ unsigned long long pls[4];      // per-wave packed partials

    int count = *counter; if (count > cap) count = cap;
    const int t    = threadIdx.x;
    const int wave = t >> 6;
    const int lane = t & 63;

    double lloss = 0.0;                        // wave0/lane0 accumulator

    for (int i = blockIdx.x; i < count; i += gridDim.x) {
        const int n  = worklist[i];
        const int bb = n >> 12, hw = n & 4095;
        if (wave == 0)
            zsh[lane] = z[(size_t)bb * DHW + (size_t)lane * HW + hw];
        __syncthreads();                       // z row visible

        // per-wave ||z||^2 (uniform value, recomputed cheaply per wave)
        const float zl = zsh[lane];
        double zn = (double)zl * (double)zl;
        #pragma unroll
        for (int m = 1; m <= 32; m <<= 1) zn += __shfl_xor(zn, m, 64);

        unsigned long long best = ~0ull;
        #pragma unroll 1
        for (int r = 0; r < 4; ++r) {
            const int k = wave * 256 + r * 64 + lane;
            const float4* cr = (const float4*)(cb + (size_t)k * DIM);
            double nj0 = 0.0, nj1 = 0.0, dt0 = 0.0, dt1 = 0.0;
            #pragma unroll 4
            for (int q = 0; q < 16; ++q) {
                const float4 c  = cr[q];
                const float4 zv = *(const float4*)&zsh[q * 4];
                nj0 = fma((double)c.x, (double)c.x, nj0);
                nj1 = fma((double)c.y, (double)c.y, nj1);
                nj0 = fma((double)c.z, (double)c.z, nj0);
                nj1 = fma((double)c.w, (double)c.w, nj1);
                dt0 = fma((double)c.x, (double)zv.x, dt0);
                dt1 = fma((double)c.y, (double)zv.y, dt1);
                dt0 = fma((double)c.z, (double)zv.z, dt0);
                dt1 = fma((double)c.w, (double)zv.w, dt1);
            }
            const double nj = nj0 + nj1;
            const double dt = dt0 + dt1;
            const double p = fmax(fma(-2.0, dt, nj) + zn, 0.0);
            const unsigned long long q64 =
                ((unsigned long long)__double_as_longlong(p) & ~1023ull)
                | (unsigned long long)k;
            if (q64 < best) best = q64;
        }

        #pragma unroll
        for (int m = 1; m <= 32; m <<= 1) {
            unsigned long long o = __shfl_xor(best, m, 64);
            if (o < best) best = o;
        }
        if (lane == 0) pls[wave] = best;
        __syncthreads();                       // partials visible

        if (wave == 0) {
            unsigned long long p0 = pls[0], p1 = pls[1];
            unsigned long long p2 = pls[2], p3 = pls[3];
            unsigned long long p = p0 < p1 ? p0 : p1;
            if (p2 < p) p = p2;
            if (p3 < p) p = p3;
            const int bk = (int)(p & 1023ull);
            out[(size_t)bb * DHW + (size_t)lane * HW + hw] = cb[(size_t)bk * DIM + lane];
            if (lane == 0)
                lloss += __longlong_as_double((long long)(p & ~1023ull));
        }
    }

    if (t == 0) lsum_ws[blockIdx.x] = lloss;   // distinct address, no RMW
}

// Stream-ordered finalize: reduce the RGRID block partials + main's loss_acc.
// Replaces the done-ticket (same-address RMW convoy) entirely.
__global__ __launch_bounds__(256) void vq_finalize(
    const double* __restrict__ lsum_ws, const double* __restrict__ loss_acc,
    float* __restrict__ loss_out)
{
    __shared__ double ws4[4];
    const int t = threadIdx.x;
    double s = 0.0;
    for (int j = t; j < RGRID; j += 256) s += lsum_ws[j];
    #pragma unroll
    for (int m = 1; m <= 32; m <<= 1) s += __shfl_xor(s, m, 64);
    if ((t & 63) == 0) ws4[t >> 6] = s;
    __syncthreads();
    if (t == 0) {
        double total = *loss_acc + ((ws4[0] + ws4[1]) + (ws4[2] + ws4[3]));
        *loss_out = (float)(1.25 * total * (1.0 / (double)((long)N_VEC * DIM)));
    }
}

extern "C" void kernel_launch(void* const* d_in, const int* in_sizes, int n_in,
                              void* d_out, int out_size, void* d_ws, size_t ws_size,
                              hipStream_t stream) {
    const float* z  = (const float*)d_in[0];
    const float* cb = (const float*)d_in[1];
    float* out      = (float*)d_out;
    char*  ws       = (char*)d_ws;

    double* loss_acc = (double*)ws;
    int*    counter  = (int*)(ws + 8);
    int*    done     = (int*)(ws + 12);
    float*  norms    = (float*)(ws + 64);
    short*  ehg      = (short*)(ws + 8192);
    short*  elg      = (short*)(ws + 139264);
    int*    worklist = (int*)(ws + 270336);
    double* lsum_ws  = (double*)(ws + 303104);   // RGRID*8 = 16 KB, ends 319488

    int cap = WLCAP;
    long avail = ((long)ws_size - 270336) / 4;
    if (avail < cap) cap = (avail > 0) ? (int)avail : 0;

    vq_prep<<<dim3(KCODE / 16), dim3(256), 0, stream>>>(
        cb, norms, ehg, elg, loss_acc, counter, done);
    vq_main<<<dim3(N_VEC / BLK_ROWS), dim3(256), 0, stream>>>(
        z, cb, norms, ehg, elg, out, loss_acc, counter, worklist, cap);
    vq_rescue<<<dim3(RGRID), dim3(256), 0, stream>>>(
        z, cb, out, counter, worklist, cap, lsum_ws);
    vq_finalize<<<dim3(1), dim3(256), 0, stream>>>(
        lsum_ws, loss_acc, out + (out_size - 1));
}

// Round 13
// 186.098 us; speedup vs baseline: 12.5799x; 1.3760x over previous
//
#include <hip/hip_runtime.h>

#define N_VEC 131072   // B*H*W
#define DIM   64
#define KCODE 1024
#define HW    4096
#define DHW   262144
#define EPS   0.125f   // near-tie margin (validated r4-r8)
#define WLCAP 8192     // count ~3700 observed; 2.2x headroom
#define BLK_ROWS 128   // rows per block; 4 waves x 32 rows
#define PITCH 72       // shorts per LDS row (144 B)
#define BCHUNK 64      // main: codes per LDS-staged codebook chunk
#define NBCHUNK 16
#define RB_VEC 4       // rescue: vectors per block-iteration
#define RGRID 1024     // rescue grid

typedef short short8 __attribute__((ext_vector_type(8)));
typedef float f32x4  __attribute__((ext_vector_type(4)));

// ws layout (bytes) -- proven 401408 footprint:
//   0      : double loss accumulator
//   8      : int flagged counter
//   12     : int done-ticket counter (unused now)
//   64     : norms f32[1024]
//   8192   : eh  bf16-bits short[65536]
//   139264 : el  bf16-bits short[65536]
//   270336 : worklist int[WLCAP]          (ends 303104)
//   303104 : lsum f64[RGRID]              (8 KB, ends 311296)

__device__ __forceinline__ unsigned short f32_to_bf16_rne(float x) {
    unsigned u = __float_as_uint(x);
    u += 0x7FFFu + ((u >> 16) & 1u);
    return (unsigned short)(u >> 16);
}
__device__ __forceinline__ float bf16_to_f32(unsigned short h) {
    return __uint_as_float((unsigned)h << 16);
}

__global__ __launch_bounds__(256) void vq_prep(
    const float* __restrict__ cb, float* __restrict__ norms,
    short* __restrict__ ehg, short* __restrict__ elg,
    double* __restrict__ loss_acc, int* __restrict__ counter,
    int* __restrict__ done)
{
    const int t = threadIdx.x;
    if (blockIdx.x == 0 && t == 0) { *loss_acc = 0.0; *counter = 0; *done = 0; }

    const int k    = blockIdx.x * 16 + (t >> 4);
    const int part = t & 15;
    const float4 v = *(const float4*)(cb + k * DIM + part * 4);

    float s = 0.f;
    s = fmaf(v.x, v.x, s); s = fmaf(v.y, v.y, s);
    s = fmaf(v.z, v.z, s); s = fmaf(v.w, v.w, s);
    #pragma unroll
    for (int m = 1; m <= 8; m <<= 1) s += __shfl_xor(s, m, 64);
    if (part == 0) norms[k] = s;

    short h[4], l[4];
    const float vv[4] = { v.x, v.y, v.z, v.w };
    #pragma unroll
    for (int j = 0; j < 4; ++j) {
        unsigned short hh = f32_to_bf16_rne(vv[j]);
        unsigned short ll = f32_to_bf16_rne(vv[j] - bf16_to_f32(hh));
        h[j] = (short)hh; l[j] = (short)ll;
    }
    *(short4*)(ehg + k * DIM + part * 4) = make_short4(h[0], h[1], h[2], h[3]);
    *(short4*)(elg + k * DIM + part * 4) = make_short4(l[0], l[1], l[2], l[3]);
}

// Main v6 (unchanged from R5/R6): LDS-staged B double-buffered, per-block LDS
// aggregation of worklist slots -> ONE global atomicAdd per block.
__global__ __launch_bounds__(256, 2) void vq_main(
    const float* __restrict__ z, const float* __restrict__ cb,
    const float* __restrict__ norms, const short* __restrict__ ehg,
    const short* __restrict__ elg, float* __restrict__ out,
    double* __restrict__ loss_acc, int* __restrict__ counter,
    int* __restrict__ worklist, int cap)
{
    __shared__ short  zh[BLK_ROWS * PITCH];   // hi(-2z) bf16 bits, [row=hw][d]
    __shared__ short  zl[BLK_ROWS * PITCH];
    __shared__ short  ebh0[BCHUNK * PITCH];   // codebook chunk hi, double-buffered
    __shared__ short  ebh1[BCHUNK * PITCH];
    __shared__ short  ebl0[BCHUNK * PITCH];
    __shared__ short  ebl1[BCHUNK * PITCH];
    __shared__ float  nsh[KCODE];             // norms, block-resident
    __shared__ int    kidx[BLK_ROWS];
    __shared__ float  wsum[4];
    __shared__ int    blkrows[BLK_ROWS];      // flagged row-local ids
    __shared__ int    blkcnt;
    __shared__ int    blkbase;

    const int t   = threadIdx.x;              // 0..255
    const int n0  = blockIdx.x * BLK_ROWS;
    const int b   = n0 >> 12;
    const int hw0 = n0 & 4095;

    const int lane = t & 63;
    const int wave = t >> 6;                  // 0..3
    const int l15  = lane & 15;
    const int quad = lane >> 4;
    const int rowbase = wave * 32;            // 2 row-tiles per wave

    if (t == 0) blkcnt = 0;

    // ---- stage z -> LDS (8 float4/thread, register transpose, b128 writes) ----
    {
        const int hwl   = (t & 31) * 4;       // 4 consecutive rows
        const int dbase = (t >> 5) * 8;       // 8 consecutive d
        float4 v[8];
        #pragma unroll
        for (int p = 0; p < 8; ++p)
            v[p] = *(const float4*)(z + (size_t)b * DHW + (size_t)(dbase + p) * HW + hw0 + hwl);
        #pragma unroll
        for (int c = 0; c < 4; ++c) {
            short8 hi, lo;
            #pragma unroll
            for (int p = 0; p < 8; ++p) {
                const float* vp = (const float*)&v[p];
                float f = -2.0f * vp[c];
                unsigned short hh = f32_to_bf16_rne(f);
                unsigned short ll = f32_to_bf16_rne(f - bf16_to_f32(hh));
                hi[p] = (short)hh; lo[p] = (short)ll;
            }
            *(short8*)&zh[(hwl + c) * PITCH + dbase] = hi;
            *(short8*)&zl[(hwl + c) * PITCH + dbase] = lo;
        }
    }

    // ---- stage norms -> LDS ----
    #pragma unroll
    for (int j = 0; j < 4; ++j) nsh[t + j * 256] = norms[t + j * 256];

    // ---- B-staging prologue: thread owns 32 B hi + 32 B lo per chunk ----
    const int cc = t >> 2;                    // code within chunk (0..63)
    const int pp = (t & 3) * 16;              // short offset within code row
    short8 pf0[4], pf1[4];                    // [0..1]=hi, [2..3]=lo
    #pragma unroll
    for (int j = 0; j < 2; ++j) {
        pf0[j]     = *(const short8*)(ehg + (size_t)cc * DIM + pp + j * 8);
        pf0[2 + j] = *(const short8*)(elg + (size_t)cc * DIM + pp + j * 8);
        pf1[j]     = *(const short8*)(ehg + (size_t)(BCHUNK + cc) * DIM + pp + j * 8);
        pf1[2 + j] = *(const short8*)(elg + (size_t)(BCHUNK + cc) * DIM + pp + j * 8);
    }
    __syncthreads();                          // z + norms ready (prologue loads drain once)

    // ---- A-fragments (32 VGPRs, resident) ----
    short8 a_h[2][2], a_l[2][2];
    #pragma unroll
    for (int rt = 0; rt < 2; ++rt)
        #pragma unroll
        for (int kt = 0; kt < 2; ++kt) {
            const int idx = (rowbase + rt * 16 + l15) * PITCH + kt * 32 + quad * 8;
            a_h[rt][kt] = *(const short8*)&zh[idx];
            a_l[rt][kt] = *(const short8*)&zl[idx];
        }

    // ---- write chunk 0 into buf0 ----
    #pragma unroll
    for (int j = 0; j < 2; ++j) {
        *(short8*)&ebh0[cc * PITCH + pp + j * 8] = pf0[j];
        *(short8*)&ebl0[cc * PITCH + pp + j * 8] = pf0[2 + j];
    }
    __syncthreads();                          // buf0 ready

    float best[2][4], best2[2][4];
    #pragma unroll
    for (int rt = 0; rt < 2; ++rt)
        #pragma unroll
        for (int r = 0; r < 4; ++r) { best[rt][r] = 3.0e38f; best2[rt][r] = 3.0e38f; }

    // chunk body: issue ch+2 loads -> pfL; compute chunk ch from (bhR,blR);
    // write pfW (chunk ch+1) -> (bhW,blW); barrier.
    auto body = [&](int ch, const short* bhR, const short* blR,
                    short* bhW, short* blW, short8 (&pfL)[4], short8 (&pfW)[4]) {
        if (ch + 2 < NBCHUNK) {
            const size_t gb = (size_t)((ch + 2) * BCHUNK + cc) * DIM + pp;
            #pragma unroll
            for (int j = 0; j < 2; ++j) {
                pfL[j]     = *(const short8*)(ehg + gb + j * 8);
                pfL[2 + j] = *(const short8*)(elg + gb + j * 8);
            }
        }
        // hoist the 4 norm reads (they gate each MFMA chain's acc init)
        float nrm4[4];
        #pragma unroll
        for (int ct = 0; ct < 4; ++ct) nrm4[ct] = nsh[ch * BCHUNK + ct * 16 + l15];

        #pragma unroll
        for (int ct = 0; ct < 4; ++ct) {
            const int crow = ct * 16 + l15;
            short8 Bh0 = *(const short8*)&bhR[crow * PITCH + quad * 8];
            short8 Bh1 = *(const short8*)&bhR[crow * PITCH + 32 + quad * 8];
            short8 Bl0 = *(const short8*)&blR[crow * PITCH + quad * 8];
            short8 Bl1 = *(const short8*)&blR[crow * PITCH + 32 + quad * 8];
            const unsigned colbits = (unsigned)(ch * BCHUNK + crow);
            const float nrm = nrm4[ct];
            #pragma unroll
            for (int rt = 0; rt < 2; ++rt) {
                f32x4 acc = { nrm, nrm, nrm, nrm };
                acc = __builtin_amdgcn_mfma_f32_16x16x32_bf16(a_h[rt][0], Bh0, acc, 0, 0, 0);
                acc = __builtin_amdgcn_mfma_f32_16x16x32_bf16(a_h[rt][1], Bh1, acc, 0, 0, 0);
                acc = __builtin_amdgcn_mfma_f32_16x16x32_bf16(a_h[rt][0], Bl0, acc, 0, 0, 0);
                acc = __builtin_amdgcn_mfma_f32_16x16x32_bf16(a_h[rt][1], Bl1, acc, 0, 0, 0);
                acc = __builtin_amdgcn_mfma_f32_16x16x32_bf16(a_l[rt][0], Bh0, acc, 0, 0, 0);
                acc = __builtin_amdgcn_mfma_f32_16x16x32_bf16(a_l[rt][1], Bh1, acc, 0, 0, 0);
                #pragma unroll
                for (int r = 0; r < 4; ++r) {
                    float p = __uint_as_float((__float_as_uint(acc[r]) & 0xFFFFFC00u) | colbits);
                    best2[rt][r] = fminf(best2[rt][r], fmaxf(best[rt][r], p));
                    best[rt][r]  = fminf(best[rt][r], p);
                }
            }
        }
        if (ch + 1 < NBCHUNK) {
            #pragma unroll
            for (int j = 0; j < 2; ++j) {
                *(short8*)&bhW[cc * PITCH + pp + j * 8] = pfW[j];
                *(short8*)&blW[cc * PITCH + pp + j * 8] = pfW[2 + j];
            }
        }
        __syncthreads();
    };

    for (int chp = 0; chp < 8; ++chp) {
        body(2 * chp,     ebh0, ebl0, ebh1, ebl1, pf0, pf1);
        body(2 * chp + 1, ebh1, ebl1, ebh0, ebl0, pf1, pf0);
    }

    // ---- merge across 16 code-lanes; each wave has complete top-2 for its rows ----
    #pragma unroll
    for (int rt = 0; rt < 2; ++rt)
        #pragma unroll
        for (int r = 0; r < 4; ++r) {
            float bb = best[rt][r], b2 = best2[rt][r];
            #pragma unroll
            for (int m = 1; m <= 8; m <<= 1) {
                float ob  = __shfl_xor(bb, m, 64);
                float ob2 = __shfl_xor(b2, m, 64);
                b2 = fminf(fminf(b2, ob2), fmaxf(bb, ob));
                bb = fminf(bb, ob);
            }
            best[rt][r] = bb; best2[rt][r] = b2;
        }

    // ---- per-row result: flags into LDS list (LDS atomics only) ----
    if (l15 == 0) {
        #pragma unroll
        for (int rt = 0; rt < 2; ++rt)
            #pragma unroll
            for (int r = 0; r < 4; ++r) {
                unsigned ub = __float_as_uint(best[rt][r]);
                int k = (int)(ub & 1023u);
                float sb  = __uint_as_float(ub & 0xFFFFFC00u);
                float sb2 = __uint_as_float(__float_as_uint(best2[rt][r]) & 0xFFFFFC00u);
                int rowl = rowbase + rt * 16 + quad * 4 + r;
                int flag = 0;
                if (sb2 - sb < EPS) {
                    int p = atomicAdd(&blkcnt, 1);   // LDS atomic, per-CU fast
                    blkrows[p] = rowl; flag = 1;
                }
                kidx[rowl] = k | (flag << 15);
            }
    }
    __syncthreads();
    // ---- ONE global atomic per block reserves the slot range ----
    if (t == 0) blkbase = (blkcnt > 0) ? atomicAdd(counter, blkcnt) : 0;
    __syncthreads();
    if (t < blkcnt) {
        const int rowl = blkrows[t];
        const int slot = blkbase + t;
        if (slot < cap) worklist[slot] = n0 + rowl;
        else            kidx[rowl] &= 0x7FFF;   // overflow: un-flag, epilogue handles
    }
    __syncthreads();

    // ---- epilogue: row = t&127, dgrp = t>>7 covers 32 d; coalesced stores ----
    float lsum = 0.f;
    {
        const int row  = t & 127;
        const int d0   = (t >> 7) * 32;
        const int ki   = kidx[row];
        const int k    = ki & 1023;
        const int flag = (ki >> 15) & 1;
        if (!flag) {
            const float4* cbr = (const float4*)(cb + k * DIM + d0);
            const short8* zhr = (const short8*)&zh[row * PITCH + d0];
            const short8* zlr = (const short8*)&zl[row * PITCH + d0];
            float* op = out + (size_t)b * DHW + (size_t)d0 * HW + hw0 + row;
            #pragma unroll
            for (int g = 0; g < 4; ++g) {
                short8 hh = zhr[g];
                short8 ll = zlr[g];
                float4 e0 = cbr[2 * g];
                float4 e1 = cbr[2 * g + 1];
                const float ev[8] = { e0.x, e0.y, e0.z, e0.w, e1.x, e1.y, e1.z, e1.w };
                #pragma unroll
                for (int j = 0; j < 8; ++j) {
                    float zv = -0.5f * (bf16_to_f32((unsigned short)hh[j]) +
                                        bf16_to_f32((unsigned short)ll[j]));
                    op[(size_t)(g * 8 + j) * HW] = ev[j];
                    float df = ev[j] - zv;
                    lsum = fmaf(df, df, lsum);
                }
            }
        }
    }
    #pragma unroll
    for (int off = 32; off > 0; off >>= 1) lsum += __shfl_down(lsum, off, 64);
    if (lane == 0) wsum[wave] = lsum;
    __syncthreads();
    if (t == 0)
        atomicAdd(loss_acc, (double)((wsum[0] + wsum[1]) + (wsum[2] + wsum[3])));
}

// Rescue v10: 4 vectors per block-iteration -- each cb row read feeds FOUR dot
// products. R12's 119 us was per-code overhead: every vmem instruction touched
// 64 distinct cache lines (rows 256 B apart) and every vector re-read the full
// 256 KB codebook (947 MB L2 + ~15M TA-cycles). Amortizing over 4 vectors cuts
// cb loads/TA work/nj 4x and gives dt[4] = 4 independent f64 chains (ILP).
// Codegen discipline kept from R11: row loop unroll 1, q loop unroll 4, all
// arrays indexed only in fully-unrolled loops (static). Loss: per-block slot
// write + stream-ordered finalize (zero same-address RMWs).
__global__ __launch_bounds__(256) void vq_rescue(
    const float* __restrict__ z, const float* __restrict__ cb,
    float* __restrict__ out,
    const int* __restrict__ counter, const int* __restrict__ worklist, int cap,
    double* __restrict__ lsum_ws)
{
    __shared__ float zsh[RB_VEC][DIM];           // 4 z rows
    __shared__ unsigned long long pls[4][RB_VEC];
    __shared__ double dsum[4];
    __shared__ int    nwl[RB_VEC];

    int count = *counter; if (count > cap) count = cap;
    const int t    = threadIdx.x;
    const int wave = t >> 6;
    const int lane = t & 63;

    double lloss = 0.0;                          // per-wave (lane0) accumulator

    for (int base = blockIdx.x * RB_VEC; base < count; base += gridDim.x * RB_VEC) {
        // ---- wave w stages z row of vector w (scattered, 1 load/thread) ----
        {
            const int i = base + wave;
            int n = -1; float zval = 0.f;
            if (i < count) {
                n = worklist[i];
                const int bb = n >> 12, hw = n & 4095;
                zval = z[(size_t)bb * DHW + (size_t)lane * HW + hw];
            }
            zsh[wave][lane] = zval;
            if (lane == 0) nwl[wave] = n;
        }
        __syncthreads();                         // all 4 z rows visible

        // ---- ||z||^2 per vector (shuffle reduce; inactive vectors -> 0) ----
        double zn[RB_VEC];
        #pragma unroll
        for (int v = 0; v < RB_VEC; ++v) {
            const float zl = zsh[v][lane];
            double s = (double)zl * (double)zl;
            #pragma unroll
            for (int m = 1; m <= 32; m <<= 1) s += __shfl_xor(s, m, 64);
            zn[v] = s;
        }

        unsigned long long best[RB_VEC];
        #pragma unroll
        for (int v = 0; v < RB_VEC; ++v) best[v] = ~0ull;

        #pragma unroll 1
        for (int r = 0; r < 4; ++r) {
            const int k = wave * 256 + r * 64 + lane;
            const float4* cr = (const float4*)(cb + (size_t)k * DIM);
            double nj0 = 0.0, nj1 = 0.0;
            double dt[RB_VEC];
            #pragma unroll
            for (int v = 0; v < RB_VEC; ++v) dt[v] = 0.0;
            #pragma unroll 4
            for (int q = 0; q < 16; ++q) {
                const float4 c = cr[q];
                nj0 = fma((double)c.x, (double)c.x, nj0);
                nj1 = fma((double)c.y, (double)c.y, nj1);
                nj0 = fma((double)c.z, (double)c.z, nj0);
                nj1 = fma((double)c.w, (double)c.w, nj1);
                #pragma unroll
                for (int v = 0; v < RB_VEC; ++v) {
                    const float4 zv = *(const float4*)&zsh[v][q * 4];
                    dt[v] = fma((double)c.x, (double)zv.x, dt[v]);
                    dt[v] = fma((double)c.y, (double)zv.y, dt[v]);
                    dt[v] = fma((double)c.z, (double)zv.z, dt[v]);
                    dt[v] = fma((double)c.w, (double)zv.w, dt[v]);
                }
            }
            const double nj = nj0 + nj1;
            #pragma unroll
            for (int v = 0; v < RB_VEC; ++v) {
                const double p = fmax(fma(-2.0, dt[v], nj) + zn[v], 0.0);
                const unsigned long long q64 =
                    ((unsigned long long)__double_as_longlong(p) & ~1023ull)
                    | (unsigned long long)k;
                if (q64 < best[v]) best[v] = q64;
            }
        }

        // ---- cross-lane min per vector ----
        #pragma unroll
        for (int v = 0; v < RB_VEC; ++v) {
            unsigned long long b = best[v];
            #pragma unroll
            for (int m = 1; m <= 32; m <<= 1) {
                unsigned long long o = __shfl_xor(b, m, 64);
                if (o < b) b = o;
            }
            if (lane == 0) pls[wave][v] = b;
        }
        __syncthreads();                         // partials visible

        // ---- wave w finalizes vector w ----
        {
            const int n = nwl[wave];
            if (n >= 0) {
                unsigned long long p0 = pls[0][wave], p1 = pls[1][wave];
                unsigned long long p2 = pls[2][wave], p3 = pls[3][wave];
                unsigned long long p = p0 < p1 ? p0 : p1;
                if (p2 < p) p = p2;
                if (p3 < p) p = p3;
                const int bk = (int)(p & 1023ull);
                const int bb = n >> 12, hw = n & 4095;
                out[(size_t)bb * DHW + (size_t)lane * HW + hw] = cb[(size_t)bk * DIM + lane];
                if (lane == 0)
                    lloss += __longlong_as_double((long long)(p & ~1023ull));
            }
        }
        __syncthreads();                         // zsh/pls safe to overwrite
    }

    if (lane == 0) dsum[wave] = lloss;
    __syncthreads();
    if (t == 0)
        lsum_ws[blockIdx.x] = (dsum[0] + dsum[1]) + (dsum[2] + dsum[3]);
}

// Stream-ordered finalize: reduce the RGRID block partials + main's loss_acc.
__global__ __launch_bounds__(256) void vq_finalize(
    const double* __restrict__ lsum_ws, const double* __restrict__ loss_acc,
    float* __restrict__ loss_out)
{
    __shared__ double ws4[4];
    const int t = threadIdx.x;
    double s = 0.0;
    for (int j = t; j < RGRID; j += 256) s += lsum_ws[j];
    #pragma unroll
    for (int m = 1; m <= 32; m <<= 1) s += __shfl_xor(s, m, 64);
    if ((t & 63) == 0) ws4[t >> 6] = s;
    __syncthreads();
    if (t == 0) {
        double total = *loss_acc + ((ws4[0] + ws4[1]) + (ws4[2] + ws4[3]));
        *loss_out = (float)(1.25 * total * (1.0 / (double)((long)N_VEC * DIM)));
    }
}

extern "C" void kernel_launch(void* const* d_in, const int* in_sizes, int n_in,
                              void* d_out, int out_size, void* d_ws, size_t ws_size,
                              hipStream_t stream) {
    const float* z  = (const float*)d_in[0];
    const float* cb = (const float*)d_in[1];
    float* out      = (float*)d_out;
    char*  ws       = (char*)d_ws;

    double* loss_acc = (double*)ws;
    int*    counter  = (int*)(ws + 8);
    int*    done     = (int*)(ws + 12);
    float*  norms    = (float*)(ws + 64);
    short*  ehg      = (short*)(ws + 8192);
    short*  elg      = (short*)(ws + 139264);
    int*    worklist = (int*)(ws + 270336);
    double* lsum_ws  = (double*)(ws + 303104);   // RGRID*8 = 8 KB, ends 311296

    int cap = WLCAP;
    long avail = ((long)ws_size - 270336) / 4;
    if (avail < cap) cap = (avail > 0) ? (int)avail : 0;

    vq_prep<<<dim3(KCODE / 16), dim3(256), 0, stream>>>(
        cb, norms, ehg, elg, loss_acc, counter, done);
    vq_main<<<dim3(N_VEC / BLK_ROWS), dim3(256), 0, stream>>>(
        z, cb, norms, ehg, elg, out, loss_acc, counter, worklist, cap);
    vq_rescue<<<dim3(RGRID), dim3(256), 0, stream>>>(
        z, cb, out, counter, worklist, cap, lsum_ws);
    vq_finalize<<<dim3(1), dim3(256), 0, stream>>>(
        lsum_ws, loss_acc, out + (out_size - 1));
}